// Round 15
// baseline (223.781 us; speedup 1.0000x reference)
//
#include <hip/hip_runtime.h>
#include <hip/hip_bf16.h>
#include <stdint.h>

typedef __attribute__((ext_vector_type(8))) short short8;
typedef __attribute__((ext_vector_type(4))) short bf4;
typedef __attribute__((ext_vector_type(4))) float f32x4;
typedef __attribute__((ext_vector_type(16))) float f32x16;

#define B_ 2
#define N1 2048
#define N2 256
#define NT 2304
#define D_ 1024
#define H_ 16
#define HD 64
// attention scale folded into Q: hd^-0.5 * log2(e)
#define QSCALE 0.18033688011112042f
#define RESCALE_THR 8.0f

static __device__ __forceinline__ float bf2f(short s){
  union { unsigned int u; float f; } u;
  u.u = ((unsigned int)(unsigned short)s) << 16;
  return u.f;
}
// round-to-nearest-even f32 -> bf16 (finite inputs)
static __device__ __forceinline__ short f2bf(float f){
  union { float f; unsigned int u; } v; v.f = f;
  unsigned int u = v.u;
  unsigned int lsb = (u >> 16) & 1u;
  u += 0x7fffu + lsb;
  return (short)(u >> 16);
}
// packed f32x2 -> bf16x2 via compiler (v_cvt_pk_bf16_f32), RNE
static __device__ __forceinline__ unsigned int cvtpk2(float a, float b){
  union { __hip_bfloat162 h; unsigned int u; } cv;
  cv.h = __float22bfloat162_rn(make_float2(a, b));
  return cv.u;
}

static __device__ __forceinline__ float fexp2(float x){
#if __has_builtin(__builtin_amdgcn_exp2f)
  return __builtin_amdgcn_exp2f(x);
#else
  return exp2f(x);
#endif
}

static __device__ __forceinline__ void gload16(const void* g, void* l){
  __builtin_amdgcn_global_load_lds(
      (const __attribute__((address_space(1))) void*)g,
      (__attribute__((address_space(3))) void*)l, 16, 0, 0);
}

// deep-swizzled short-index into a [64 rows][8 chunks of 8 shorts] LDS tile:
// slot = chunk ^ (row&7) ^ (row>>3)  (rows 0..63) -> 32-row column reads
// (rows r, r+8, r+16, r+24 at same chunk) hit 4 distinct 16B slots.
static __device__ __forceinline__ int swz(int row, int chunk){
  return (row << 6) + (((chunk ^ (row & 7) ^ ((row >> 3) & 7)) & 7) << 3);
}

// ---------------- fp32 -> bf16 convert (x and c fused; outputs contiguous) --
__global__ __launch_bounds__(256) void k_cvt_all(const float* __restrict__ x,
                                                 const float* __restrict__ c,
                                                 short* __restrict__ out){
  int i = (blockIdx.x * 256 + threadIdx.x) * 8;
  const float* in = (i < 4194304) ? (x + i) : (c + (i - 4194304));
  float4 a = *(const float4*)(in);
  float4 b = *(const float4*)(in + 4);
  short8 o;
  o[0]=f2bf(a.x); o[1]=f2bf(a.y); o[2]=f2bf(a.z); o[3]=f2bf(a.w);
  o[4]=f2bf(b.x); o[5]=f2bf(b.y); o[6]=f2bf(b.z); o[7]=f2bf(b.w);
  *(short8*)(out + i) = o;
}

// ---------------- W (K x N, f32) -> Wt (N x K, bf16), 4 matrices fused -----
__global__ __launch_bounds__(256) void k_transpose_w4(
    const float* __restrict__ Wq1, const float* __restrict__ Wq2,
    const float* __restrict__ Wp1, const float* __restrict__ Wp2,
    short* __restrict__ Wt1, short* __restrict__ Wt2,
    short* __restrict__ Wtp1, short* __restrict__ Wtp2){
  const int id = blockIdx.x;
  const float* W; short* Wt; int N; int bx, by;
  if (id < 768)      { W = Wq1; Wt = Wt1;  N = 3072; bx = id % 48;          by = id / 48; }
  else if (id < 1536){ W = Wq2; Wt = Wt2;  N = 3072; bx = (id-768) % 48;    by = (id-768) / 48; }
  else if (id < 1792){ W = Wp1; Wt = Wtp1; N = 1024; bx = (id-1536) % 16;   by = (id-1536) / 16; }
  else               { W = Wp2; Wt = Wtp2; N = 1024; bx = (id-1792) % 16;   by = (id-1792) / 16; }
  const int K = 1024;
  __shared__ float tl[64][65];
  const int n0 = bx * 64, k0 = by * 64;
  const int t = threadIdx.x, r = t >> 2, c = (t & 3) * 16;
  const float* src = W + (size_t)(k0 + r) * N + n0 + c;
  #pragma unroll
  for (int i = 0; i < 16; i += 4){
    float4 v = *(const float4*)(src + i);
    tl[r][c+i] = v.x; tl[r][c+i+1] = v.y; tl[r][c+i+2] = v.z; tl[r][c+i+3] = v.w;
  }
  __syncthreads();
  short8 o0, o1;
  #pragma unroll
  for (int i = 0; i < 8; i++) o0[i] = f2bf(tl[c+i][r]);
  #pragma unroll
  for (int i = 0; i < 8; i++) o1[i] = f2bf(tl[c+8+i][r]);
  short* dst = Wt + (size_t)(n0 + r) * K + k0 + c;
  *(short8*)(dst)     = o0;
  *(short8*)(dst + 8) = o1;
}

// ---------------- fused QKV GEMM + bias + LN + RoPE + split + V-transpose --
__global__ __launch_bounds__(256) void k_gemm_qkv(const short* __restrict__ A,
    const short* __restrict__ Bt, const short* __restrict__ Bt2,
    const float* __restrict__ bias, const float* __restrict__ bias2,
    const float* __restrict__ qn1w, const float* __restrict__ qn1b,
    const float* __restrict__ kn1w, const float* __restrict__ kn1b,
    const float* __restrict__ qn2w, const float* __restrict__ qn2b,
    const float* __restrict__ kn2w, const float* __restrict__ kn2b,
    const float* __restrict__ fcos, const float* __restrict__ fsin,
    short* __restrict__ Qo, short* __restrict__ Ko, short* __restrict__ Vto){
  __shared__ __align__(16) short As[128*32];
  __shared__ __align__(16) short Bs[128*32];
  const int t = threadIdx.x;
  const int w = t >> 6, l = t & 63;
  const int lc = l & 15, g = l >> 4;
  const int gx = gridDim.x;                 // 24
  const int nb = gx * gridDim.y;            // 864
  const int bid = blockIdx.y * gx + blockIdx.x;
  const int nbid = (bid & 7) * (nb >> 3) + (bid >> 3);
  const int tm = (nbid / gx) * 128, tn = (nbid % gx) * 128;
  const int wm = (w >> 1) * 64, wn = (w & 1) * 64;
  const int K = 1024;
  const bool s1 = (tm < 4096);

  const short* Bsel = s1 ? Bt : Bt2;
  const float* bsel = s1 ? bias : bias2;

  const int r0 = w*32 + (l >> 2);
  const int r1 = r0 + 16;
  const int cb = (l & 3) * 16;

  const char* Ag0 = (const char*)(A + (size_t)(tm + r0) * K) + cb;
  const char* Ag1 = (const char*)(A + (size_t)(tm + r1) * K) + cb;
  const char* Bg0 = (const char*)(Bsel + (size_t)(tn + r0) * K) + cb;
  const char* Bg1 = (const char*)(Bsel + (size_t)(tn + r1) * K) + cb;
  char* Al0 = (char*)As + (w*2  )*1024;
  char* Al1 = (char*)As + (w*2+1)*1024;
  char* Bl0 = (char*)Bs + (w*2  )*1024;
  char* Bl1 = (char*)Bs + (w*2+1)*1024;

  f32x4 acc[4][4];
  #pragma unroll
  for (int m=0;m<4;m++){
    #pragma unroll
    for (int n=0;n<4;n++){ acc[m][n][0]=0.f; acc[m][n][1]=0.f; acc[m][n][2]=0.f; acc[m][n][3]=0.f; }
  }

  for (int k0 = 0; k0 < K; k0 += 32){
    const int kb = k0 * 2;
    gload16(Ag0 + kb, Al0);
    gload16(Ag1 + kb, Al1);
    gload16(Bg0 + kb, Bl0);
    gload16(Bg1 + kb, Bl1);
    __syncthreads();
    short8 af[4], bfr[4];
    #pragma unroll
    for (int m=0;m<4;m++) af[m]  = *(const short8*)(As + (wm + m*16 + lc)*32 + g*8);
    #pragma unroll
    for (int n=0;n<4;n++) bfr[n] = *(const short8*)(Bs + (wn + n*16 + lc)*32 + g*8);
    #pragma unroll
    for (int m=0;m<4;m++){
      #pragma unroll
      for (int n=0;n<4;n++)
        acc[m][n] = __builtin_amdgcn_mfma_f32_16x16x32_bf16(af[m], bfr[n], acc[m][n], 0, 0, 0);
    }
    __syncthreads();
  }

  // ---- bias add (f32) ----
  #pragma unroll
  for (int n=0;n<4;n++){
    const float bv = bsel[tn + wn + n*16 + lc];
    #pragma unroll
    for (int m=0;m<4;m++){
      acc[m][n][0] += bv; acc[m][n][1] += bv; acc[m][n][2] += bv; acc[m][n][3] += bv;
    }
  }

  const int colbase = tn + wn;              // multiple of 64
  const int grp = colbase >> 10;            // 0=Q, 1=K, 2=V
  const int hh = (colbase & 1023) >> 6;     // head

  if (grp == 2){
    // ---- V: pass-through, transposed store (b,h,64,NT) ----
    #pragma unroll
    for (int m=0;m<4;m++){
      const int row0 = tm + wm + m*16 + g*4;
      const int bb  = s1 ? (row0 >> 11) : ((row0 - 4096) >> 8);
      const int pos = s1 ? (row0 & 2047) : (2048 + ((row0 - 4096) & 255));
      short* vbase = Vto + (size_t)(bb*16 + hh) * 64 * NT + pos;
      #pragma unroll
      for (int n=0;n<4;n++){
        const int d = n*16 + lc;
        bf4 ov;
        #pragma unroll
        for (int r=0;r<4;r++) ov[r] = f2bf(acc[m][n][r]);
        *(bf4*)(vbase + (size_t)d * NT) = ov;
      }
    }
    return;
  }

  // ---- Q/K: LN (+RoPE for stream1), write (b,h,NT,64) ----
  const float* lnw = (grp == 0) ? (s1 ? qn1w : qn2w) : (s1 ? kn1w : kn2w);
  const float* lnb = (grp == 0) ? (s1 ? qn1b : qn2b) : (s1 ? kn1b : kn2b);
  short* outp = (grp == 0) ? Qo : Ko;
  float wv_[4], bv_[4];
  #pragma unroll
  for (int n=0;n<4;n++){ wv_[n] = lnw[n*16 + lc]; bv_[n] = lnb[n*16 + lc]; }

  #pragma unroll
  for (int m=0;m<4;m++){
    float mu[4], rv[4];
    #pragma unroll
    for (int r=0;r<4;r++){
      float s  = (acc[m][0][r] + acc[m][1][r]) + (acc[m][2][r] + acc[m][3][r]);
      float sq = (acc[m][0][r]*acc[m][0][r] + acc[m][1][r]*acc[m][1][r])
               + (acc[m][2][r]*acc[m][2][r] + acc[m][3][r]*acc[m][3][r]);
      s  += __shfl_xor(s, 1, 64);  sq += __shfl_xor(sq, 1, 64);
      s  += __shfl_xor(s, 2, 64);  sq += __shfl_xor(sq, 2, 64);
      s  += __shfl_xor(s, 4, 64);  sq += __shfl_xor(sq, 4, 64);
      s  += __shfl_xor(s, 8, 64);  sq += __shfl_xor(sq, 8, 64);
      mu[r] = s * (1.f/64.f);
      const float var = sq * (1.f/64.f) - mu[r]*mu[r];
      rv[r] = rsqrtf(var + 1e-5f);
    }
    const int row0 = tm + wm + m*16 + g*4;
    const int bb  = s1 ? (row0 >> 11) : ((row0 - 4096) >> 8);
    const int pos0 = s1 ? (row0 & 2047) : (2048 + ((row0 - 4096) & 255));
    short* obase = outp + ((size_t)(bb*16 + hh) * NT + pos0) * 64;
    #pragma unroll
    for (int n=0;n<4;n++){
      float xh[4];
      #pragma unroll
      for (int r=0;r<4;r++) xh[r] = (acc[m][n][r] - mu[r]) * rv[r] * wv_[n] + bv_[n];
      if (s1){
        #pragma unroll
        for (int r=0;r<4;r++){
          const size_t fi = (size_t)(pos0 + r) * 32 + n*8 + (lc >> 1);
          const float cv = fcos[fi];
          const float sv = fsin[fi];
          const float p = __shfl_xor(xh[r], 1, 64);
          xh[r] = (lc & 1) ? (p*sv + xh[r]*cv) : (xh[r]*cv - p*sv);
        }
      }
      if (grp == 0){
        #pragma unroll
        for (int r=0;r<4;r++) xh[r] *= QSCALE;
      }
      const int d = n*16 + lc;
      #pragma unroll
      for (int r=0;r<4;r++) obase[(size_t)r * 64 + d] = f2bf(xh[r]);
    }
  }
}

// ---------------- proj GEMM: C[M,N] = A[M,K] * Bt[N,K]^T + bias (f32 out) --
__global__ __launch_bounds__(256) void k_gemm_proj(const short* __restrict__ A,
                                                   const short* __restrict__ Bt,
                                                   const short* __restrict__ Bt2,
                                                   const float* __restrict__ bias,
                                                   const float* __restrict__ bias2,
                                                   float* __restrict__ Cp,
                                                   int N, int K, int Msplit){
  __shared__ __align__(16) short As[128*32];
  __shared__ __align__(16) short Bs[128*32];
  const int t = threadIdx.x;
  const int w = t >> 6, l = t & 63;
  const int lc = l & 15, g = l >> 4;
  const int gx = gridDim.x;
  const int nb = gx * gridDim.y;
  const int bid = blockIdx.y * gx + blockIdx.x;
  const int nbid = (bid & 7) * (nb >> 3) + (bid >> 3);
  const int tm = (nbid / gx) * 128, tn = (nbid % gx) * 128;
  const int wm = (w >> 1) * 64, wn = (w & 1) * 64;

  const short* Bsel = (tm < Msplit) ? Bt : Bt2;
  const float* bsel = (tm < Msplit) ? bias : bias2;

  const int r0 = w*32 + (l >> 2);
  const int r1 = r0 + 16;
  const int cb = (l & 3) * 16;

  const char* Ag0 = (const char*)(A + (size_t)(tm + r0) * K) + cb;
  const char* Ag1 = (const char*)(A + (size_t)(tm + r1) * K) + cb;
  const char* Bg0 = (const char*)(Bsel + (size_t)(tn + r0) * K) + cb;
  const char* Bg1 = (const char*)(Bsel + (size_t)(tn + r1) * K) + cb;
  char* Al0 = (char*)As + (w*2  )*1024;
  char* Al1 = (char*)As + (w*2+1)*1024;
  char* Bl0 = (char*)Bs + (w*2  )*1024;
  char* Bl1 = (char*)Bs + (w*2+1)*1024;

  f32x4 acc[4][4];
  #pragma unroll
  for (int m=0;m<4;m++){
    #pragma unroll
    for (int n=0;n<4;n++){ acc[m][n][0]=0.f; acc[m][n][1]=0.f; acc[m][n][2]=0.f; acc[m][n][3]=0.f; }
  }

  for (int k0 = 0; k0 < K; k0 += 32){
    const int kb = k0 * 2;
    gload16(Ag0 + kb, Al0);
    gload16(Ag1 + kb, Al1);
    gload16(Bg0 + kb, Bl0);
    gload16(Bg1 + kb, Bl1);
    __syncthreads();
    short8 af[4], bfr[4];
    #pragma unroll
    for (int m=0;m<4;m++) af[m]  = *(const short8*)(As + (wm + m*16 + lc)*32 + g*8);
    #pragma unroll
    for (int n=0;n<4;n++) bfr[n] = *(const short8*)(Bs + (wn + n*16 + lc)*32 + g*8);
    #pragma unroll
    for (int m=0;m<4;m++){
      #pragma unroll
      for (int n=0;n<4;n++)
        acc[m][n] = __builtin_amdgcn_mfma_f32_16x16x32_bf16(af[m], bfr[n], acc[m][n], 0, 0, 0);
    }
    __syncthreads();
  }

  #pragma unroll
  for (int n=0;n<4;n++){
    const int col = tn + wn + n*16 + lc;
    const float bv = bsel[col];
    #pragma unroll
    for (int m=0;m<4;m++){
      const int row = tm + wm + m*16 + g*4;
      #pragma unroll
      for (int r=0;r<4;r++)
        Cp[(size_t)(row + r)*N + col] = acc[m][n][r] + bv;
    }
  }
}

// ---------------- flash attention: 32x32 MFMA, P never touches LDS --------
// 576 blocks = 32 bh x 18 q-tiles of 128 rows, XCD-chunked (4 bh/XCD).
// 4 waves x 64; wave w owns q-cols qt*128 + w*32 + (l&31). KVBLK=64.
// QK^T swapped: S^T = mfma_32x32x16(K, Q): lane holds S[kv][q=l&31],
// kv = (reg&3)+8*(reg>>2)+4*(l>>5) per 32-kv block -> softmax in-lane over
// 32 regs + one shfl_xor(32). PV swapped: O^T = mfma(V^T, P^T); P B-frag
// built in-register: 4 cvtpk2 + 4 shfl_xor(32) + cndmask per 16-kv slice
// (lane h5 takes regs 8sb..8sb+3 from h5''=0, 8sb+4..7 from h5''=1).
// K/V staged by global_load_lds DMA (linear dest, inverse-swz source, G21).
// LDS = K dbuf 16K + V dbuf 16K = 32KB; no Ps buffer.
__global__ __launch_bounds__(256) void k_attn(const short* __restrict__ Q,
                                              const short* __restrict__ Kg,
                                              const short* __restrict__ Vt,
                                              short* __restrict__ o1,
                                              short* __restrict__ o2){
  __shared__ __align__(16) short Kl[2][4096];
  __shared__ __align__(16) short Vl[2][4096];
  const int t = threadIdx.x, w = t >> 6, l = t & 63;
  const int q32 = l & 31, h5 = l >> 5;
  const int blk = blockIdx.x;
  const int ch = blk & 7, ii = blk >> 3;    // 576 = 8 * 72
  const int bh = ch * 4 + (ii / 18);        // 4 bh per XCD-chunk
  const int qt = ii % 18;
  const int b = bh >> 4, hh = bh & 15;
  const int qrow = qt*128 + w*32 + q32;
  const short* Qb = Q  + (size_t)bh * NT * HD;
  const short* Kb = Kg + (size_t)bh * NT * HD;
  const short* Vb = Vt + (size_t)bh * HD * NT;

  // Q fragments (B-operand): col q=qrow, k = hk*16 + h5*8 + e
  short8 qf[4];
  #pragma unroll
  for (int hk=0;hk<4;hk++)
    qf[hk] = *(const short8*)(Qb + (size_t)qrow * HD + hk*16 + h5*8);

  // DMA staging: instr i in {0,1}: dest rows (w*2+i)*8 + (l>>3), slot l&7;
  // source logical chunk = slot ^ (row&7) ^ (row>>3)  (inverse of swz)
  const int srow0 = w*16 + (l >> 3);
  const int srow1 = srow0 + 8;
  const int cg0 = (l & 7) ^ (srow0 & 7) ^ ((srow0 >> 3) & 7);
  const int cg1 = (l & 7) ^ (srow1 & 7) ^ ((srow1 >> 3) & 7);
  const short* Kg0 = Kb + (size_t)srow0 * HD + cg0*8;
  const short* Kg1 = Kb + (size_t)srow1 * HD + cg1*8;
  const short* Vg0 = Vb + (size_t)srow0 * NT + cg0*8;
  const short* Vg1 = Vb + (size_t)srow1 * NT + cg1*8;
  const int ld0 = w*1024, ld1 = w*1024 + 512;   // wave-uniform LDS short idx

  float mcur = -1e30f, lcur = 0.f;
  f32x16 oacc[2];
  #pragma unroll
  for (int db=0;db<2;db++){
    #pragma unroll
    for (int r=0;r<16;r++) oacc[db][r] = 0.f;
  }

  // prologue: stage tile 0 into buffer 0
  gload16(Kg0, (char*)&Kl[0][ld0]);
  gload16(Kg1, (char*)&Kl[0][ld1]);
  gload16(Vg0, (char*)&Vl[0][ld0]);
  gload16(Vg1, (char*)&Vl[0][ld1]);
  __syncthreads();

  for (int pi = 0; pi < 36; ++pi){
    const int cur = pi & 1;
    // issue next tile's DMA early (lands before the end-of-iter barrier)
    if (pi < 35){
      const size_t ko = (size_t)(pi + 1) * 64 * HD;
      const int vo = (pi + 1) * 64;
      gload16(Kg0 + ko, (char*)&Kl[cur ^ 1][ld0]);
      gload16(Kg1 + ko, (char*)&Kl[cur ^ 1][ld1]);
      gload16(Vg0 + vo, (char*)&Vl[cur ^ 1][ld0]);
      gload16(Vg1 + vo, (char*)&Vl[cur ^ 1][ld1]);
    }
    // ---- S^T: 2 kv-blocks x 4 hd-slices ----
    f32x16 s[2];
    __builtin_amdgcn_s_setprio(1);
    #pragma unroll
    for (int kvb=0;kvb<2;kvb++){
      f32x16 a;
      #pragma unroll
      for (int r=0;r<16;r++) a[r] = 0.f;
      #pragma unroll
      for (int hk=0;hk<4;hk++){
        short8 kf = *(const short8*)(&Kl[cur][swz(kvb*32 + q32, hk*2 + h5)]);
        a = __builtin_amdgcn_mfma_f32_32x32x16_bf16(kf, qf[hk], a, 0, 0, 0);
      }
      s[kvb] = a;
    }
    __builtin_amdgcn_s_setprio(0);
    // ---- lane-local softmax for q-col q32 (32 regs + 1 cross-half) ----
    float tmx = -1e30f;
    #pragma unroll
    for (int kvb=0;kvb<2;kvb++){
      #pragma unroll
      for (int r=0;r<16;r++) tmx = fmaxf(tmx, s[kvb][r]);
    }
    tmx = fmaxf(tmx, __shfl_xor(tmx, 32, 64));
    float mn = mcur;
    if (__any(tmx > mcur + RESCALE_THR)){
      mn = fmaxf(mcur, tmx);
      const float fsc = fexp2(mcur - mn);
      mcur = mn;
      lcur *= fsc;
      #pragma unroll
      for (int db=0;db<2;db++){
        #pragma unroll
        for (int r=0;r<16;r++) oacc[db][r] *= fsc;
      }
    }
    float rs = 0.f;
    #pragma unroll
    for (int kvb=0;kvb<2;kvb++){
      #pragma unroll
      for (int r=0;r<16;r++){
        s[kvb][r] = fexp2(s[kvb][r] - mn);
        rs += s[kvb][r];
      }
    }
    rs += __shfl_xor(rs, 32, 64);
    lcur += rs;
    // ---- PV: P B-frag in-register per 16-kv slice; 2 d-blocks each ----
    #pragma unroll
    for (int kvs=0;kvs<4;kvs++){
      const int kvb = kvs >> 1, sb = kvs & 1;
      const unsigned int A0 = cvtpk2(s[kvb][8*sb+0], s[kvb][8*sb+1]);
      const unsigned int A1 = cvtpk2(s[kvb][8*sb+2], s[kvb][8*sb+3]);
      const unsigned int B0 = cvtpk2(s[kvb][8*sb+4], s[kvb][8*sb+5]);
      const unsigned int B1 = cvtpk2(s[kvb][8*sb+6], s[kvb][8*sb+7]);
      const unsigned int X0 = (unsigned int)__shfl_xor((int)A0, 32, 64);
      const unsigned int X1 = (unsigned int)__shfl_xor((int)A1, 32, 64);
      const unsigned int Y0 = (unsigned int)__shfl_xor((int)B0, 32, 64);
      const unsigned int Y1 = (unsigned int)__shfl_xor((int)B1, 32, 64);
      union { unsigned int u[4]; short8 s8; } pf;
      pf.u[0] = h5 ? Y0 : A0;
      pf.u[1] = h5 ? Y1 : A1;
      pf.u[2] = h5 ? B0 : X0;
      pf.u[3] = h5 ? B1 : X1;
      __builtin_amdgcn_s_setprio(1);
      #pragma unroll
      for (int db=0;db<2;db++){
        short8 vf = *(const short8*)(&Vl[cur][swz(db*32 + q32, kvs*2 + h5)]);
        oacc[db] = __builtin_amdgcn_mfma_f32_32x32x16_bf16(vf, pf.s8, oacc[db], 0, 0, 0);
      }
      __builtin_amdgcn_s_setprio(0);
    }
    __syncthreads();
  }

  // ---- epilogue: normalize (lane-local) and write ----
  const float inv = 1.0f / lcur;
  const int qi = qrow;
  short* obase = (qi < N1) ? (o1 + ((size_t)b * N1 + qi) * D_)
                           : (o2 + ((size_t)b * N2 + (qi - N1)) * D_);
  #pragma unroll
  for (int db=0;db<2;db++){
    #pragma unroll
    for (int rg=0;rg<4;rg++){
      bf4 ov;
      #pragma unroll
      for (int i=0;i<4;i++) ov[i] = f2bf(oacc[db][rg*4 + i] * inv);
      *(bf4*)(obase + hh*64 + db*32 + rg*8 + h5*4) = ov;
    }
  }
}

extern "C" void kernel_launch(void* const* d_in, const int* in_sizes, int n_in,
                              void* d_out, int out_size, void* d_ws, size_t ws_size,
                              hipStream_t stream){
  const float* x    = (const float*)d_in[0];
  const float* c    = (const float*)d_in[1];
  const float* fc   = (const float*)d_in[2];
  const float* fs   = (const float*)d_in[3];
  const float* Wq1  = (const float*)d_in[4];
  const float* bq1  = (const float*)d_in[5];
  const float* Wq2  = (const float*)d_in[6];
  const float* bq2  = (const float*)d_in[7];
  const float* qn1w = (const float*)d_in[8];
  const float* qn1b = (const float*)d_in[9];
  const float* kn1w = (const float*)d_in[10];
  const float* kn1b = (const float*)d_in[11];
  const float* qn2w = (const float*)d_in[12];
  const float* qn2b = (const float*)d_in[13];
  const float* kn2w = (const float*)d_in[14];
  const float* kn2b = (const float*)d_in[15];
  const float* Wp1  = (const float*)d_in[16];
  const float* bp1  = (const float*)d_in[17];
  const float* Wp2  = (const float*)d_in[18];
  const float* bp2  = (const float*)d_in[19];
  float* out = (float*)d_out;

  char* ws = (char*)d_ws;
  short* xb   = (short*)(ws);                       // 8,388,608 + cb 1,048,576 contiguous
  short* Wt1  = (short*)(ws + 9437184);             // 6,291,456
  short* Wt2  = (short*)(ws + 15728640);            // 6,291,456
  short* Wtp1 = (short*)(ws + 22020096);            // 2,097,152
  short* Wtp2 = (short*)(ws + 24117248);            // 2,097,152
  short* o1   = (short*)(ws + 26214400);            // 8,388,608 (+o2 1,048,576 contiguous)
  short* Vtb  = (short*)(ws + 26214400 + 9437184);  // 9,437,184
  short* Qb   = (short*)(ws + 54525952);            // 9,437,184
  short* Kb   = (short*)(ws + 63963136);            // 9,437,184

  k_cvt_all<<<2304, 256, 0, stream>>>(x, c, xb);
  k_transpose_w4<<<2048, 256, 0, stream>>>(Wq1, Wq2, Wp1, Wp2, Wt1, Wt2, Wtp1, Wtp2);

  // fused QKV GEMM + bias + LN + RoPE + split + V-transpose
  k_gemm_qkv<<<dim3(24,36), 256, 0, stream>>>(xb, Wt1, Wt2, bq1, bq2,
      qn1w, qn1b, kn1w, kn1b, qn2w, qn2b, kn2w, kn2b, fc, fs, Qb, Kb, Vtb);

  k_attn<<<576, 256, 0, stream>>>(Qb, Kb, Vtb, o1, o1 + 4194304);

  // fused projection GEMM: A = [o1; o2] (4608 x 1024), rows >= 4096 use Wtp2/bp2
  k_gemm_proj<<<dim3(8,36), 256, 0, stream>>>(o1, Wtp1, Wtp2, bp1, bp2, out, 1024, 1024, 4096);
}

// Round 16
// 188.795 us; speedup vs baseline: 1.1853x; 1.1853x over previous
//
#include <hip/hip_runtime.h>
#include <hip/hip_bf16.h>
#include <stdint.h>

typedef __attribute__((ext_vector_type(8))) short short8;
typedef __attribute__((ext_vector_type(4))) short bf4;
typedef __attribute__((ext_vector_type(4))) float f32x4;

#define B_ 2
#define N1 2048
#define N2 256
#define NT 2304
#define D_ 1024
#define H_ 16
#define HD 64
// attention scale folded into Q: hd^-0.5 * log2(e)
#define QSCALE 0.18033688011112042f
#define RESCALE_THR 8.0f

static __device__ __forceinline__ float bf2f(short s){
  union { unsigned int u; float f; } u;
  u.u = ((unsigned int)(unsigned short)s) << 16;
  return u.f;
}
// round-to-nearest-even f32 -> bf16 (finite inputs)
static __device__ __forceinline__ short f2bf(float f){
  union { float f; unsigned int u; } v; v.f = f;
  unsigned int u = v.u;
  unsigned int lsb = (u >> 16) & 1u;
  u += 0x7fffu + lsb;
  return (short)(u >> 16);
}
// packed f32x2 -> bf16x2 via compiler (v_cvt_pk_bf16_f32), RNE
static __device__ __forceinline__ unsigned int cvtpk2(float a, float b){
  union { __hip_bfloat162 h; unsigned int u; } cv;
  cv.h = __float22bfloat162_rn(make_float2(a, b));
  return cv.u;
}

static __device__ __forceinline__ float fexp2(float x){
#if __has_builtin(__builtin_amdgcn_exp2f)
  return __builtin_amdgcn_exp2f(x);
#else
  return exp2f(x);
#endif
}

static __device__ __forceinline__ void gload16(const void* g, void* l){
  __builtin_amdgcn_global_load_lds(
      (const __attribute__((address_space(1))) void*)g,
      (__attribute__((address_space(3))) void*)l, 16, 0, 0);
}

// swizzled short-index into a [rows][8 chunks of 8 shorts] LDS tile (row stride 64)
static __device__ __forceinline__ int swz(int row, int chunk){
  return (row << 6) + ((chunk ^ (row & 7)) << 3);
}

// ---------------- fp32 -> bf16 convert (x and c fused; outputs contiguous) --
__global__ __launch_bounds__(256) void k_cvt_all(const float* __restrict__ x,
                                                 const float* __restrict__ c,
                                                 short* __restrict__ out){
  int i = (blockIdx.x * 256 + threadIdx.x) * 8;
  const float* in = (i < 4194304) ? (x + i) : (c + (i - 4194304));
  float4 a = *(const float4*)(in);
  float4 b = *(const float4*)(in + 4);
  short8 o;
  o[0]=f2bf(a.x); o[1]=f2bf(a.y); o[2]=f2bf(a.z); o[3]=f2bf(a.w);
  o[4]=f2bf(b.x); o[5]=f2bf(b.y); o[6]=f2bf(b.z); o[7]=f2bf(b.w);
  *(short8*)(out + i) = o;
}

// ---------------- W (K x N, f32) -> Wt (N x K, bf16), 4 matrices fused -----
__global__ __launch_bounds__(256) void k_transpose_w4(
    const float* __restrict__ Wq1, const float* __restrict__ Wq2,
    const float* __restrict__ Wp1, const float* __restrict__ Wp2,
    short* __restrict__ Wt1, short* __restrict__ Wt2,
    short* __restrict__ Wtp1, short* __restrict__ Wtp2){
  const int id = blockIdx.x;
  const float* W; short* Wt; int N; int bx, by;
  if (id < 768)      { W = Wq1; Wt = Wt1;  N = 3072; bx = id % 48;          by = id / 48; }
  else if (id < 1536){ W = Wq2; Wt = Wt2;  N = 3072; bx = (id-768) % 48;    by = (id-768) / 48; }
  else if (id < 1792){ W = Wp1; Wt = Wtp1; N = 1024; bx = (id-1536) % 16;   by = (id-1536) / 16; }
  else               { W = Wp2; Wt = Wtp2; N = 1024; bx = (id-1792) % 16;   by = (id-1792) / 16; }
  const int K = 1024;
  __shared__ float tl[64][65];
  const int n0 = bx * 64, k0 = by * 64;
  const int t = threadIdx.x, r = t >> 2, c = (t & 3) * 16;
  const float* src = W + (size_t)(k0 + r) * N + n0 + c;
  #pragma unroll
  for (int i = 0; i < 16; i += 4){
    float4 v = *(const float4*)(src + i);
    tl[r][c+i] = v.x; tl[r][c+i+1] = v.y; tl[r][c+i+2] = v.z; tl[r][c+i+3] = v.w;
  }
  __syncthreads();
  short8 o0, o1;
  #pragma unroll
  for (int i = 0; i < 8; i++) o0[i] = f2bf(tl[c+i][r]);
  #pragma unroll
  for (int i = 0; i < 8; i++) o1[i] = f2bf(tl[c+8+i][r]);
  short* dst = Wt + (size_t)(n0 + r) * K + k0 + c;
  *(short8*)(dst)     = o0;
  *(short8*)(dst + 8) = o1;
}

// ---------------- fused QKV GEMM + bias + LN + RoPE + split + V-transpose --
__global__ __launch_bounds__(256) void k_gemm_qkv(const short* __restrict__ A,
    const short* __restrict__ Bt, const short* __restrict__ Bt2,
    const float* __restrict__ bias, const float* __restrict__ bias2,
    const float* __restrict__ qn1w, const float* __restrict__ qn1b,
    const float* __restrict__ kn1w, const float* __restrict__ kn1b,
    const float* __restrict__ qn2w, const float* __restrict__ qn2b,
    const float* __restrict__ kn2w, const float* __restrict__ kn2b,
    const float* __restrict__ fcos, const float* __restrict__ fsin,
    short* __restrict__ Qo, short* __restrict__ Ko, short* __restrict__ Vto){
  __shared__ __align__(16) short As[128*32];
  __shared__ __align__(16) short Bs[128*32];
  const int t = threadIdx.x;
  const int w = t >> 6, l = t & 63;
  const int lc = l & 15, g = l >> 4;
  const int gx = gridDim.x;                 // 24
  const int nb = gx * gridDim.y;            // 864
  const int bid = blockIdx.y * gx + blockIdx.x;
  const int nbid = (bid & 7) * (nb >> 3) + (bid >> 3);
  const int tm = (nbid / gx) * 128, tn = (nbid % gx) * 128;
  const int wm = (w >> 1) * 64, wn = (w & 1) * 64;
  const int K = 1024;
  const bool s1 = (tm < 4096);

  const short* Bsel = s1 ? Bt : Bt2;
  const float* bsel = s1 ? bias : bias2;

  const int r0 = w*32 + (l >> 2);
  const int r1 = r0 + 16;
  const int cb = (l & 3) * 16;

  const char* Ag0 = (const char*)(A + (size_t)(tm + r0) * K) + cb;
  const char* Ag1 = (const char*)(A + (size_t)(tm + r1) * K) + cb;
  const char* Bg0 = (const char*)(Bsel + (size_t)(tn + r0) * K) + cb;
  const char* Bg1 = (const char*)(Bsel + (size_t)(tn + r1) * K) + cb;
  char* Al0 = (char*)As + (w*2  )*1024;
  char* Al1 = (char*)As + (w*2+1)*1024;
  char* Bl0 = (char*)Bs + (w*2  )*1024;
  char* Bl1 = (char*)Bs + (w*2+1)*1024;

  f32x4 acc[4][4];
  #pragma unroll
  for (int m=0;m<4;m++){
    #pragma unroll
    for (int n=0;n<4;n++){ acc[m][n][0]=0.f; acc[m][n][1]=0.f; acc[m][n][2]=0.f; acc[m][n][3]=0.f; }
  }

  for (int k0 = 0; k0 < K; k0 += 32){
    const int kb = k0 * 2;
    gload16(Ag0 + kb, Al0);
    gload16(Ag1 + kb, Al1);
    gload16(Bg0 + kb, Bl0);
    gload16(Bg1 + kb, Bl1);
    __syncthreads();
    short8 af[4], bfr[4];
    #pragma unroll
    for (int m=0;m<4;m++) af[m]  = *(const short8*)(As + (wm + m*16 + lc)*32 + g*8);
    #pragma unroll
    for (int n=0;n<4;n++) bfr[n] = *(const short8*)(Bs + (wn + n*16 + lc)*32 + g*8);
    #pragma unroll
    for (int m=0;m<4;m++){
      #pragma unroll
      for (int n=0;n<4;n++)
        acc[m][n] = __builtin_amdgcn_mfma_f32_16x16x32_bf16(af[m], bfr[n], acc[m][n], 0, 0, 0);
    }
    __syncthreads();
  }

  // ---- bias add (f32) ----
  #pragma unroll
  for (int n=0;n<4;n++){
    const float bv = bsel[tn + wn + n*16 + lc];
    #pragma unroll
    for (int m=0;m<4;m++){
      acc[m][n][0] += bv; acc[m][n][1] += bv; acc[m][n][2] += bv; acc[m][n][3] += bv;
    }
  }

  const int colbase = tn + wn;              // multiple of 64
  const int grp = colbase >> 10;            // 0=Q, 1=K, 2=V
  const int hh = (colbase & 1023) >> 6;     // head

  if (grp == 2){
    // ---- V: pass-through, transposed store (b,h,64,NT) ----
    #pragma unroll
    for (int m=0;m<4;m++){
      const int row0 = tm + wm + m*16 + g*4;
      const int bb  = s1 ? (row0 >> 11) : ((row0 - 4096) >> 8);
      const int pos = s1 ? (row0 & 2047) : (2048 + ((row0 - 4096) & 255));
      short* vbase = Vto + (size_t)(bb*16 + hh) * 64 * NT + pos;
      #pragma unroll
      for (int n=0;n<4;n++){
        const int d = n*16 + lc;
        bf4 ov;
        #pragma unroll
        for (int r=0;r<4;r++) ov[r] = f2bf(acc[m][n][r]);
        *(bf4*)(vbase + (size_t)d * NT) = ov;
      }
    }
    return;
  }

  // ---- Q/K: LN (+RoPE for stream1), write (b,h,NT,64) ----
  const float* lnw = (grp == 0) ? (s1 ? qn1w : qn2w) : (s1 ? kn1w : kn2w);
  const float* lnb = (grp == 0) ? (s1 ? qn1b : qn2b) : (s1 ? kn1b : kn2b);
  short* outp = (grp == 0) ? Qo : Ko;
  float wv_[4], bv_[4];
  #pragma unroll
  for (int n=0;n<4;n++){ wv_[n] = lnw[n*16 + lc]; bv_[n] = lnb[n*16 + lc]; }

  #pragma unroll
  for (int m=0;m<4;m++){
    float mu[4], rv[4];
    #pragma unroll
    for (int r=0;r<4;r++){
      float s  = (acc[m][0][r] + acc[m][1][r]) + (acc[m][2][r] + acc[m][3][r]);
      float sq = (acc[m][0][r]*acc[m][0][r] + acc[m][1][r]*acc[m][1][r])
               + (acc[m][2][r]*acc[m][2][r] + acc[m][3][r]*acc[m][3][r]);
      s  += __shfl_xor(s, 1, 64);  sq += __shfl_xor(sq, 1, 64);
      s  += __shfl_xor(s, 2, 64);  sq += __shfl_xor(sq, 2, 64);
      s  += __shfl_xor(s, 4, 64);  sq += __shfl_xor(sq, 4, 64);
      s  += __shfl_xor(s, 8, 64);  sq += __shfl_xor(sq, 8, 64);
      mu[r] = s * (1.f/64.f);
      const float var = sq * (1.f/64.f) - mu[r]*mu[r];
      rv[r] = rsqrtf(var + 1e-5f);
    }
    const int row0 = tm + wm + m*16 + g*4;
    const int bb  = s1 ? (row0 >> 11) : ((row0 - 4096) >> 8);
    const int pos0 = s1 ? (row0 & 2047) : (2048 + ((row0 - 4096) & 255));
    short* obase = outp + ((size_t)(bb*16 + hh) * NT + pos0) * 64;
    #pragma unroll
    for (int n=0;n<4;n++){
      float xh[4];
      #pragma unroll
      for (int r=0;r<4;r++) xh[r] = (acc[m][n][r] - mu[r]) * rv[r] * wv_[n] + bv_[n];
      if (s1){
        #pragma unroll
        for (int r=0;r<4;r++){
          const size_t fi = (size_t)(pos0 + r) * 32 + n*8 + (lc >> 1);
          const float cv = fcos[fi];
          const float sv = fsin[fi];
          const float p = __shfl_xor(xh[r], 1, 64);
          xh[r] = (lc & 1) ? (p*sv + xh[r]*cv) : (xh[r]*cv - p*sv);
        }
      }
      if (grp == 0){
        #pragma unroll
        for (int r=0;r<4;r++) xh[r] *= QSCALE;
      }
      const int d = n*16 + lc;
      #pragma unroll
      for (int r=0;r<4;r++) obase[(size_t)r * 64 + d] = f2bf(xh[r]);
    }
  }
}

// ---------------- proj GEMM: C[M,N] = A[M,K] * Bt[N,K]^T + bias (f32 out) --
__global__ __launch_bounds__(256) void k_gemm_proj(const short* __restrict__ A,
                                                   const short* __restrict__ Bt,
                                                   const short* __restrict__ Bt2,
                                                   const float* __restrict__ bias,
                                                   const float* __restrict__ bias2,
                                                   float* __restrict__ Cp,
                                                   int N, int K, int Msplit){
  __shared__ __align__(16) short As[128*32];
  __shared__ __align__(16) short Bs[128*32];
  const int t = threadIdx.x;
  const int w = t >> 6, l = t & 63;
  const int lc = l & 15, g = l >> 4;
  const int gx = gridDim.x;
  const int nb = gx * gridDim.y;
  const int bid = blockIdx.y * gx + blockIdx.x;
  const int nbid = (bid & 7) * (nb >> 3) + (bid >> 3);
  const int tm = (nbid / gx) * 128, tn = (nbid % gx) * 128;
  const int wm = (w >> 1) * 64, wn = (w & 1) * 64;

  const short* Bsel = (tm < Msplit) ? Bt : Bt2;
  const float* bsel = (tm < Msplit) ? bias : bias2;

  const int r0 = w*32 + (l >> 2);
  const int r1 = r0 + 16;
  const int cb = (l & 3) * 16;

  const char* Ag0 = (const char*)(A + (size_t)(tm + r0) * K) + cb;
  const char* Ag1 = (const char*)(A + (size_t)(tm + r1) * K) + cb;
  const char* Bg0 = (const char*)(Bsel + (size_t)(tn + r0) * K) + cb;
  const char* Bg1 = (const char*)(Bsel + (size_t)(tn + r1) * K) + cb;
  char* Al0 = (char*)As + (w*2  )*1024;
  char* Al1 = (char*)As + (w*2+1)*1024;
  char* Bl0 = (char*)Bs + (w*2  )*1024;
  char* Bl1 = (char*)Bs + (w*2+1)*1024;

  f32x4 acc[4][4];
  #pragma unroll
  for (int m=0;m<4;m++){
    #pragma unroll
    for (int n=0;n<4;n++){ acc[m][n][0]=0.f; acc[m][n][1]=0.f; acc[m][n][2]=0.f; acc[m][n][3]=0.f; }
  }

  for (int k0 = 0; k0 < K; k0 += 32){
    const int kb = k0 * 2;
    gload16(Ag0 + kb, Al0);
    gload16(Ag1 + kb, Al1);
    gload16(Bg0 + kb, Bl0);
    gload16(Bg1 + kb, Bl1);
    __syncthreads();
    short8 af[4], bfr[4];
    #pragma unroll
    for (int m=0;m<4;m++) af[m]  = *(const short8*)(As + (wm + m*16 + lc)*32 + g*8);
    #pragma unroll
    for (int n=0;n<4;n++) bfr[n] = *(const short8*)(Bs + (wn + n*16 + lc)*32 + g*8);
    #pragma unroll
    for (int m=0;m<4;m++){
      #pragma unroll
      for (int n=0;n<4;n++)
        acc[m][n] = __builtin_amdgcn_mfma_f32_16x16x32_bf16(af[m], bfr[n], acc[m][n], 0, 0, 0);
    }
    __syncthreads();
  }

  #pragma unroll
  for (int n=0;n<4;n++){
    const int col = tn + wn + n*16 + lc;
    const float bv = bsel[col];
    #pragma unroll
    for (int m=0;m<4;m++){
      const int row = tm + wm + m*16 + g*4;
      #pragma unroll
      for (int r=0;r<4;r++)
        Cp[(size_t)(row + r)*N + col] = acc[m][n][r] + bv;
    }
  }
}

// ---------------- flash attention: r14 structure + DMA staging ------------
// 576 blocks = 32 bh x 18 q-tiles of 128 rows, XCD-chunked (4 bh/XCD).
// 8 waves x 64; wave w owns q-rows qt*128 + w*16 + [0,16). KVBLK=128,
// joint softmax (r14-verified). K [128][64] swz dbuf; V 2x[64][64] swz
// dbuf; Ps [8][1024] reused across halves.
// Staging via global_load_lds DMA (linear dest = base + lane*16B,
// inverse-swz per-lane SOURCE, G21 / r15-verified): zero LDS write bank
// conflicts (r15 PMC: SQ_LDS_BANK_CONFLICT=0), no prefetch VGPRs. The
// end-of-iter __syncthreads vmcnt-drain guarantees landing (r15 schedule).
__global__ __launch_bounds__(512) void k_attn(const short* __restrict__ Q,
                                              const short* __restrict__ Kg,
                                              const short* __restrict__ Vt,
                                              short* __restrict__ o1,
                                              short* __restrict__ o2){
  __shared__ __align__(16) short Kl[2][8192];
  __shared__ __align__(16) short Vl[2][2][4096];
  __shared__ __align__(16) short Ps[8][1024];
  const int t = threadIdx.x, w = t >> 6, l = t & 63;
  const int lc = l & 15, g = l >> 4;
  const int blk = blockIdx.x;
  const int ch = blk & 7, ii = blk >> 3;    // 576 = 8 * 72
  const int bh = ch * 4 + (ii / 18);        // 4 bh per XCD-chunk
  const int qt = ii % 18;
  const int b = bh >> 4, hh = bh & 15;
  const int q0 = qt * 128 + w * 16;
  const short* Qb = Q  + (size_t)bh * NT * HD;
  const short* Kb = Kg + (size_t)bh * NT * HD;
  const short* Vb = Vt + (size_t)bh * HD * NT;

  // Q fragment (B-operand): col q=lc, k-elems = head-dims g*8.. / +32
  short8 qf0 = *(const short8*)(Qb + (size_t)(q0 + lc) * HD + g*8);
  short8 qf1 = *(const short8*)(Qb + (size_t)(q0 + lc) * HD + g*8 + 32);

  // ---- K DMA roles: instr i in {0,1}: dest short idx (w*2+i)*512 + l*8
  //      -> row (w*2+i)*8 + (l>>3), slot l&7; source chunk = slot^(row&7)
  const int krow0 = w*16 + (l >> 3);       // i=0 rows 16w..16w+7
  const int krow1 = krow0 + 8;             // i=1 rows 16w+8..16w+15
  const int kc0 = (l & 7) ^ (krow0 & 7);
  const int kc1 = (l & 7) ^ (krow1 & 7);
  const short* Kg0 = Kb + (size_t)krow0 * HD + kc0*8;
  const short* Kg1 = Kb + (size_t)krow1 * HD + kc1*8;
  const int kld0 = (w*2  )*512 + 0;        // + l*16B implicit (lane scatter)
  const int kld1 = (w*2+1)*512 + 0;
  // ---- V DMA roles: half h: dest short idx w*512 + l*8 in Vl[buf][h]
  //      -> row w*8 + (l>>3), slot l&7; source chunk = slot^(row&7)
  const int vrow = w*8 + (l >> 3);
  const int vc = (l & 7) ^ (vrow & 7);
  const short* Vg = Vb + (size_t)vrow * NT + vc*8;   // + pi*128 + h*64
  const int vld = w*512;

  float mcur = -1e30f, lcur = 0.f;
  f32x4 oacc[4];
  #pragma unroll
  for (int j=0;j<4;j++){ oacc[j][0]=0.f; oacc[j][1]=0.f; oacc[j][2]=0.f; oacc[j][3]=0.f; }

  // prologue: DMA-stage pair 0 into buffer 0
  gload16(Kg0, (char*)&Kl[0][kld0]);
  gload16(Kg1, (char*)&Kl[0][kld1]);
  gload16(Vg,       (char*)&Vl[0][0][vld]);
  gload16(Vg + 64,  (char*)&Vl[0][1][vld]);
  __syncthreads();

  for (int pi = 0; pi < 18; ++pi){
    const int cur = pi & 1;
    // issue next pair's DMA early (lands before end-of-iter barrier drain)
    if (pi < 17){
      const size_t ko = (size_t)(pi + 1) * 128 * HD;
      const int vo = (pi + 1) * 128;
      gload16(Kg0 + ko, (char*)&Kl[cur ^ 1][kld0]);
      gload16(Kg1 + ko, (char*)&Kl[cur ^ 1][kld1]);
      gload16(Vg + vo,      (char*)&Vl[cur ^ 1][0][vld]);
      gload16(Vg + vo + 64, (char*)&Vl[cur ^ 1][1][vld]);
    }
    // ---- S^T over 128 kv: s[j][r] = S[q=lc][kv = pi*128 + 16j + 4g + r] ----
    f32x4 s[8];
    __builtin_amdgcn_s_setprio(1);
    #pragma unroll
    for (int j=0;j<8;j++){
      const int row = j*16 + lc;
      short8 k0 = *(const short8*)(&Kl[cur][swz(row, g)]);
      short8 k1 = *(const short8*)(&Kl[cur][swz(row, g + 4)]);
      f32x4 a; a[0]=0.f; a[1]=0.f; a[2]=0.f; a[3]=0.f;
      a = __builtin_amdgcn_mfma_f32_16x16x32_bf16(k0, qf0, a, 0, 0, 0);
      a = __builtin_amdgcn_mfma_f32_16x16x32_bf16(k1, qf1, a, 0, 0, 0);
      s[j] = a;
    }
    __builtin_amdgcn_s_setprio(0);
    // ---- joint lane-local softmax over 128 kv for q-row lc ----
    float tj[8];
    #pragma unroll
    for (int j=0;j<8;j++)
      tj[j] = fmaxf(fmaxf(s[j][0], s[j][1]), fmaxf(s[j][2], s[j][3]));
    float tmx = fmaxf(fmaxf(fmaxf(tj[0], tj[1]), fmaxf(tj[2], tj[3])),
                      fmaxf(fmaxf(tj[4], tj[5]), fmaxf(tj[6], tj[7])));
    tmx = fmaxf(tmx, __shfl_xor(tmx, 16, 64));
    tmx = fmaxf(tmx, __shfl_xor(tmx, 32, 64));
    float mn = mcur;
    if (__any(tmx > mcur + RESCALE_THR)){
      mn = fmaxf(mcur, tmx);
      const float fsc = fexp2(mcur - mn);
      mcur = mn;
      lcur *= fsc;
      #pragma unroll
      for (int j=0;j<4;j++){
        oacc[j][0] *= fsc; oacc[j][1] *= fsc; oacc[j][2] *= fsc; oacc[j][3] *= fsc;
      }
    }
    // p = exp2(s - mn), in place
    #pragma unroll
    for (int j=0;j<8;j++){
      s[j][0] = fexp2(s[j][0] - mn);
      s[j][1] = fexp2(s[j][1] - mn);
      s[j][2] = fexp2(s[j][2] - mn);
      s[j][3] = fexp2(s[j][3] - mn);
    }
    float rs = 0.f;
    #pragma unroll
    for (int j=0;j<8;j++)
      rs += (s[j][0] + s[j][1]) + (s[j][2] + s[j][3]);
    rs += __shfl_xor(rs, 16, 64);
    rs += __shfl_xor(rs, 32, 64);
    lcur += rs;
    // ---- two 64-kv halves: P-write then PV (Ps reused; same-wave order) ----
    #pragma unroll
    for (int h=0;h<2;h++){
      #pragma unroll
      for (int j=0;j<4;j++){
        const int si = (lc << 6) + (((2*j + (g >> 1)) ^ (lc & 7)) << 3) + (g & 1) * 4;
        unsigned int* dst = (unsigned int*)&Ps[w][si];
        dst[0] = cvtpk2(s[h*4+j][0], s[h*4+j][1]);
        dst[1] = cvtpk2(s[h*4+j][2], s[h*4+j][3]);
      }
      #pragma unroll
      for (int kk=0;kk<2;kk++){
        short8 pa = *(const short8*)(&Ps[w][swz(lc, 4*kk + g)]);
        __builtin_amdgcn_s_setprio(1);
        #pragma unroll
        for (int jd=0;jd<4;jd++){
          short8 vb = *(const short8*)(&Vl[cur][h][swz(lc + 16*jd, 4*kk + g)]);
          oacc[jd] = __builtin_amdgcn_mfma_f32_16x16x32_bf16(vb, pa, oacc[jd], 0, 0, 0);
        }
        __builtin_amdgcn_s_setprio(0);
      }
    }
    __syncthreads();  // drains DMA (vmcnt 0) + all waves done with buf cur
  }

  // ---- epilogue: normalize (lane-local) and write ----
  const float inv = 1.0f / lcur;
  const int qi = q0 + lc;
  short* obase = (qi < N1) ? (o1 + ((size_t)b * N1 + qi) * D_)
                           : (o2 + ((size_t)b * N2 + (qi - N1)) * D_);
  #pragma unroll
  for (int jd=0;jd<4;jd++){
    bf4 ov;
    #pragma unroll
    for (int r=0;r<4;r++) ov[r] = f2bf(oacc[jd][r] * inv);
    *(bf4*)(obase + hh*64 + 16*jd + 4*g) = ov;
  }
}

extern "C" void kernel_launch(void* const* d_in, const int* in_sizes, int n_in,
                              void* d_out, int out_size, void* d_ws, size_t ws_size,
                              hipStream_t stream){
  const float* x    = (const float*)d_in[0];
  const float* c    = (const float*)d_in[1];
  const float* fc   = (const float*)d_in[2];
  const float* fs   = (const float*)d_in[3];
  const float* Wq1  = (const float*)d_in[4];
  const float* bq1  = (const float*)d_in[5];
  const float* Wq2  = (const float*)d_in[6];
  const float* bq2  = (const float*)d_in[7];
  const float* qn1w = (const float*)d_in[8];
  const float* qn1b = (const float*)d_in[9];
  const float* kn1w = (const float*)d_in[10];
  const float* kn1b = (const float*)d_in[11];
  const float* qn2w = (const float*)d_in[12];
  const float* qn2b = (const float*)d_in[13];
  const float* kn2w = (const float*)d_in[14];
  const float* kn2b = (const float*)d_in[15];
  const float* Wp1  = (const float*)d_in[16];
  const float* bp1  = (const float*)d_in[17];
  const float* Wp2  = (const float*)d_in[18];
  const float* bp2  = (const float*)d_in[19];
  float* out = (float*)d_out;

  char* ws = (char*)d_ws;
  short* xb   = (short*)(ws);                       // 8,388,608 + cb 1,048,576 contiguous
  short* Wt1  = (short*)(ws + 9437184);             // 6,291,456
  short* Wt2  = (short*)(ws + 15728640);            // 6,291,456
  short* Wtp1 = (short*)(ws + 22020096);            // 2,097,152
  short* Wtp2 = (short*)(ws + 24117248);            // 2,097,152
  short* o1   = (short*)(ws + 26214400);            // 8,388,608 (+o2 1,048,576 contiguous)
  short* Vtb  = (short*)(ws + 26214400 + 9437184);  // 9,437,184
  short* Qb   = (short*)(ws + 54525952);            // 9,437,184
  short* Kb   = (short*)(ws + 63963136);            // 9,437,184

  k_cvt_all<<<2304, 256, 0, stream>>>(x, c, xb);
  k_transpose_w4<<<2048, 256, 0, stream>>>(Wq1, Wq2, Wp1, Wp2, Wt1, Wt2, Wtp1, Wtp2);

  // fused QKV GEMM + bias + LN + RoPE + split + V-transpose
  k_gemm_qkv<<<dim3(24,36), 256, 0, stream>>>(xb, Wt1, Wt2, bq1, bq2,
      qn1w, qn1b, kn1w, kn1b, qn2w, qn2b, kn2w, kn2b, fc, fs, Qb, Kb, Vtb);

  k_attn<<<576, 512, 0, stream>>>(Qb, Kb, Vtb, o1, o1 + 4194304);

  // fused projection GEMM: A = [o1; o2] (4608 x 1024), rows >= 4096 use Wtp2/bp2
  k_gemm_proj<<<dim3(8,36), 256, 0, stream>>>(o1, Wtp1, Wtp2, bp1, bp2, out, 1024, 1024, 4096);
}

// Round 17
// 184.825 us; speedup vs baseline: 1.2108x; 1.0215x over previous
//
#include <hip/hip_runtime.h>
#include <hip/hip_bf16.h>
#include <stdint.h>

typedef __attribute__((ext_vector_type(8))) short short8;
typedef __attribute__((ext_vector_type(4))) short bf4;
typedef __attribute__((ext_vector_type(4))) float f32x4;

#define B_ 2
#define N1 2048
#define N2 256
#define NT 2304
#define D_ 1024
#define H_ 16
#define HD 64
// attention scale folded into Q: hd^-0.5 * log2(e)
#define QSCALE 0.18033688011112042f
#define RESCALE_THR 8.0f

static __device__ __forceinline__ float bf2f(short s){
  union { unsigned int u; float f; } u;
  u.u = ((unsigned int)(unsigned short)s) << 16;
  return u.f;
}
// round-to-nearest-even f32 -> bf16 (finite inputs)
static __device__ __forceinline__ short f2bf(float f){
  union { float f; unsigned int u; } v; v.f = f;
  unsigned int u = v.u;
  unsigned int lsb = (u >> 16) & 1u;
  u += 0x7fffu + lsb;
  return (short)(u >> 16);
}
// packed f32x2 -> bf16x2 via compiler (v_cvt_pk_bf16_f32), RNE
static __device__ __forceinline__ unsigned int cvtpk2(float a, float b){
  union { __hip_bfloat162 h; unsigned int u; } cv;
  cv.h = __float22bfloat162_rn(make_float2(a, b));
  return cv.u;
}

static __device__ __forceinline__ float fexp2(float x){
#if __has_builtin(__builtin_amdgcn_exp2f)
  return __builtin_amdgcn_exp2f(x);
#else
  return exp2f(x);
#endif
}

static __device__ __forceinline__ void gload16(const void* g, void* l){
  __builtin_amdgcn_global_load_lds(
      (const __attribute__((address_space(1))) void*)g,
      (__attribute__((address_space(3))) void*)l, 16, 0, 0);
}

// swizzled short-index into a [rows][8 chunks of 8 shorts] LDS tile (row stride 64)
static __device__ __forceinline__ int swz(int row, int chunk){
  return (row << 6) + ((chunk ^ (row & 7)) << 3);
}

// ---------------- fp32 -> bf16 convert (x and c fused; outputs contiguous) --
__global__ __launch_bounds__(256) void k_cvt_all(const float* __restrict__ x,
                                                 const float* __restrict__ c,
                                                 short* __restrict__ out){
  int i = (blockIdx.x * 256 + threadIdx.x) * 8;
  const float* in = (i < 4194304) ? (x + i) : (c + (i - 4194304));
  float4 a = *(const float4*)(in);
  float4 b = *(const float4*)(in + 4);
  short8 o;
  o[0]=f2bf(a.x); o[1]=f2bf(a.y); o[2]=f2bf(a.z); o[3]=f2bf(a.w);
  o[4]=f2bf(b.x); o[5]=f2bf(b.y); o[6]=f2bf(b.z); o[7]=f2bf(b.w);
  *(short8*)(out + i) = o;
}

// ---------------- W (K x N, f32) -> Wt (N x K, bf16), 4 matrices fused -----
__global__ __launch_bounds__(256) void k_transpose_w4(
    const float* __restrict__ Wq1, const float* __restrict__ Wq2,
    const float* __restrict__ Wp1, const float* __restrict__ Wp2,
    short* __restrict__ Wt1, short* __restrict__ Wt2,
    short* __restrict__ Wtp1, short* __restrict__ Wtp2){
  const int id = blockIdx.x;
  const float* W; short* Wt; int N; int bx, by;
  if (id < 768)      { W = Wq1; Wt = Wt1;  N = 3072; bx = id % 48;          by = id / 48; }
  else if (id < 1536){ W = Wq2; Wt = Wt2;  N = 3072; bx = (id-768) % 48;    by = (id-768) / 48; }
  else if (id < 1792){ W = Wp1; Wt = Wtp1; N = 1024; bx = (id-1536) % 16;   by = (id-1536) / 16; }
  else               { W = Wp2; Wt = Wtp2; N = 1024; bx = (id-1792) % 16;   by = (id-1792) / 16; }
  const int K = 1024;
  __shared__ float tl[64][65];
  const int n0 = bx * 64, k0 = by * 64;
  const int t = threadIdx.x, r = t >> 2, c = (t & 3) * 16;
  const float* src = W + (size_t)(k0 + r) * N + n0 + c;
  #pragma unroll
  for (int i = 0; i < 16; i += 4){
    float4 v = *(const float4*)(src + i);
    tl[r][c+i] = v.x; tl[r][c+i+1] = v.y; tl[r][c+i+2] = v.z; tl[r][c+i+3] = v.w;
  }
  __syncthreads();
  short8 o0, o1;
  #pragma unroll
  for (int i = 0; i < 8; i++) o0[i] = f2bf(tl[c+i][r]);
  #pragma unroll
  for (int i = 0; i < 8; i++) o1[i] = f2bf(tl[c+8+i][r]);
  short* dst = Wt + (size_t)(n0 + r) * K + k0 + c;
  *(short8*)(dst)     = o0;
  *(short8*)(dst + 8) = o1;
}

// ---------------- fused QKV GEMM + bias + LN + RoPE + split + V-transpose --
__global__ __launch_bounds__(256) void k_gemm_qkv(const short* __restrict__ A,
    const short* __restrict__ Bt, const short* __restrict__ Bt2,
    const float* __restrict__ bias, const float* __restrict__ bias2,
    const float* __restrict__ qn1w, const float* __restrict__ qn1b,
    const float* __restrict__ kn1w, const float* __restrict__ kn1b,
    const float* __restrict__ qn2w, const float* __restrict__ qn2b,
    const float* __restrict__ kn2w, const float* __restrict__ kn2b,
    const float* __restrict__ fcos, const float* __restrict__ fsin,
    short* __restrict__ Qo, short* __restrict__ Ko, short* __restrict__ Vto){
  __shared__ __align__(16) short As[128*32];
  __shared__ __align__(16) short Bs[128*32];
  const int t = threadIdx.x;
  const int w = t >> 6, l = t & 63;
  const int lc = l & 15, g = l >> 4;
  const int gx = gridDim.x;                 // 24
  const int nb = gx * gridDim.y;            // 864
  const int bid = blockIdx.y * gx + blockIdx.x;
  const int nbid = (bid & 7) * (nb >> 3) + (bid >> 3);
  const int tm = (nbid / gx) * 128, tn = (nbid % gx) * 128;
  const int wm = (w >> 1) * 64, wn = (w & 1) * 64;
  const int K = 1024;
  const bool s1 = (tm < 4096);

  const short* Bsel = s1 ? Bt : Bt2;
  const float* bsel = s1 ? bias : bias2;

  const int r0 = w*32 + (l >> 2);
  const int r1 = r0 + 16;
  const int cb = (l & 3) * 16;

  const char* Ag0 = (const char*)(A + (size_t)(tm + r0) * K) + cb;
  const char* Ag1 = (const char*)(A + (size_t)(tm + r1) * K) + cb;
  const char* Bg0 = (const char*)(Bsel + (size_t)(tn + r0) * K) + cb;
  const char* Bg1 = (const char*)(Bsel + (size_t)(tn + r1) * K) + cb;
  char* Al0 = (char*)As + (w*2  )*1024;
  char* Al1 = (char*)As + (w*2+1)*1024;
  char* Bl0 = (char*)Bs + (w*2  )*1024;
  char* Bl1 = (char*)Bs + (w*2+1)*1024;

  f32x4 acc[4][4];
  #pragma unroll
  for (int m=0;m<4;m++){
    #pragma unroll
    for (int n=0;n<4;n++){ acc[m][n][0]=0.f; acc[m][n][1]=0.f; acc[m][n][2]=0.f; acc[m][n][3]=0.f; }
  }

  for (int k0 = 0; k0 < K; k0 += 32){
    const int kb = k0 * 2;
    gload16(Ag0 + kb, Al0);
    gload16(Ag1 + kb, Al1);
    gload16(Bg0 + kb, Bl0);
    gload16(Bg1 + kb, Bl1);
    __syncthreads();
    short8 af[4], bfr[4];
    #pragma unroll
    for (int m=0;m<4;m++) af[m]  = *(const short8*)(As + (wm + m*16 + lc)*32 + g*8);
    #pragma unroll
    for (int n=0;n<4;n++) bfr[n] = *(const short8*)(Bs + (wn + n*16 + lc)*32 + g*8);
    #pragma unroll
    for (int m=0;m<4;m++){
      #pragma unroll
      for (int n=0;n<4;n++)
        acc[m][n] = __builtin_amdgcn_mfma_f32_16x16x32_bf16(af[m], bfr[n], acc[m][n], 0, 0, 0);
    }
    __syncthreads();
  }

  // ---- bias add (f32) ----
  #pragma unroll
  for (int n=0;n<4;n++){
    const float bv = bsel[tn + wn + n*16 + lc];
    #pragma unroll
    for (int m=0;m<4;m++){
      acc[m][n][0] += bv; acc[m][n][1] += bv; acc[m][n][2] += bv; acc[m][n][3] += bv;
    }
  }

  const int colbase = tn + wn;              // multiple of 64
  const int grp = colbase >> 10;            // 0=Q, 1=K, 2=V
  const int hh = (colbase & 1023) >> 6;     // head

  if (grp == 2){
    // ---- V: pass-through, transposed store (b,h,64,NT) ----
    #pragma unroll
    for (int m=0;m<4;m++){
      const int row0 = tm + wm + m*16 + g*4;
      const int bb  = s1 ? (row0 >> 11) : ((row0 - 4096) >> 8);
      const int pos = s1 ? (row0 & 2047) : (2048 + ((row0 - 4096) & 255));
      short* vbase = Vto + (size_t)(bb*16 + hh) * 64 * NT + pos;
      #pragma unroll
      for (int n=0;n<4;n++){
        const int d = n*16 + lc;
        bf4 ov;
        #pragma unroll
        for (int r=0;r<4;r++) ov[r] = f2bf(acc[m][n][r]);
        *(bf4*)(vbase + (size_t)d * NT) = ov;
      }
    }
    return;
  }

  // ---- Q/K: LN (+RoPE for stream1), write (b,h,NT,64) ----
  const float* lnw = (grp == 0) ? (s1 ? qn1w : qn2w) : (s1 ? kn1w : kn2w);
  const float* lnb = (grp == 0) ? (s1 ? qn1b : qn2b) : (s1 ? kn1b : kn2b);
  short* outp = (grp == 0) ? Qo : Ko;
  float wv_[4], bv_[4];
  #pragma unroll
  for (int n=0;n<4;n++){ wv_[n] = lnw[n*16 + lc]; bv_[n] = lnb[n*16 + lc]; }

  #pragma unroll
  for (int m=0;m<4;m++){
    float mu[4], rv[4];
    #pragma unroll
    for (int r=0;r<4;r++){
      float s  = (acc[m][0][r] + acc[m][1][r]) + (acc[m][2][r] + acc[m][3][r]);
      float sq = (acc[m][0][r]*acc[m][0][r] + acc[m][1][r]*acc[m][1][r])
               + (acc[m][2][r]*acc[m][2][r] + acc[m][3][r]*acc[m][3][r]);
      s  += __shfl_xor(s, 1, 64);  sq += __shfl_xor(sq, 1, 64);
      s  += __shfl_xor(s, 2, 64);  sq += __shfl_xor(sq, 2, 64);
      s  += __shfl_xor(s, 4, 64);  sq += __shfl_xor(sq, 4, 64);
      s  += __shfl_xor(s, 8, 64);  sq += __shfl_xor(sq, 8, 64);
      mu[r] = s * (1.f/64.f);
      const float var = sq * (1.f/64.f) - mu[r]*mu[r];
      rv[r] = rsqrtf(var + 1e-5f);
    }
    const int row0 = tm + wm + m*16 + g*4;
    const int bb  = s1 ? (row0 >> 11) : ((row0 - 4096) >> 8);
    const int pos0 = s1 ? (row0 & 2047) : (2048 + ((row0 - 4096) & 255));
    short* obase = outp + ((size_t)(bb*16 + hh) * NT + pos0) * 64;
    #pragma unroll
    for (int n=0;n<4;n++){
      float xh[4];
      #pragma unroll
      for (int r=0;r<4;r++) xh[r] = (acc[m][n][r] - mu[r]) * rv[r] * wv_[n] + bv_[n];
      if (s1){
        #pragma unroll
        for (int r=0;r<4;r++){
          const size_t fi = (size_t)(pos0 + r) * 32 + n*8 + (lc >> 1);
          const float cv = fcos[fi];
          const float sv = fsin[fi];
          const float p = __shfl_xor(xh[r], 1, 64);
          xh[r] = (lc & 1) ? (p*sv + xh[r]*cv) : (xh[r]*cv - p*sv);
        }
      }
      if (grp == 0){
        #pragma unroll
        for (int r=0;r<4;r++) xh[r] *= QSCALE;
      }
      const int d = n*16 + lc;
      #pragma unroll
      for (int r=0;r<4;r++) obase[(size_t)r * 64 + d] = f2bf(xh[r]);
    }
  }
}

// ---------------- proj GEMM: C[M,N] = A[M,K] * Bt[N,K]^T + bias (f32 out) --
__global__ __launch_bounds__(256) void k_gemm_proj(const short* __restrict__ A,
                                                   const short* __restrict__ Bt,
                                                   const short* __restrict__ Bt2,
                                                   const float* __restrict__ bias,
                                                   const float* __restrict__ bias2,
                                                   float* __restrict__ Cp,
                                                   int N, int K, int Msplit){
  __shared__ __align__(16) short As[128*32];
  __shared__ __align__(16) short Bs[128*32];
  const int t = threadIdx.x;
  const int w = t >> 6, l = t & 63;
  const int lc = l & 15, g = l >> 4;
  const int gx = gridDim.x;
  const int nb = gx * gridDim.y;
  const int bid = blockIdx.y * gx + blockIdx.x;
  const int nbid = (bid & 7) * (nb >> 3) + (bid >> 3);
  const int tm = (nbid / gx) * 128, tn = (nbid % gx) * 128;
  const int wm = (w >> 1) * 64, wn = (w & 1) * 64;

  const short* Bsel = (tm < Msplit) ? Bt : Bt2;
  const float* bsel = (tm < Msplit) ? bias : bias2;

  const int r0 = w*32 + (l >> 2);
  const int r1 = r0 + 16;
  const int cb = (l & 3) * 16;

  const char* Ag0 = (const char*)(A + (size_t)(tm + r0) * K) + cb;
  const char* Ag1 = (const char*)(A + (size_t)(tm + r1) * K) + cb;
  const char* Bg0 = (const char*)(Bsel + (size_t)(tn + r0) * K) + cb;
  const char* Bg1 = (const char*)(Bsel + (size_t)(tn + r1) * K) + cb;
  char* Al0 = (char*)As + (w*2  )*1024;
  char* Al1 = (char*)As + (w*2+1)*1024;
  char* Bl0 = (char*)Bs + (w*2  )*1024;
  char* Bl1 = (char*)Bs + (w*2+1)*1024;

  f32x4 acc[4][4];
  #pragma unroll
  for (int m=0;m<4;m++){
    #pragma unroll
    for (int n=0;n<4;n++){ acc[m][n][0]=0.f; acc[m][n][1]=0.f; acc[m][n][2]=0.f; acc[m][n][3]=0.f; }
  }

  for (int k0 = 0; k0 < K; k0 += 32){
    const int kb = k0 * 2;
    gload16(Ag0 + kb, Al0);
    gload16(Ag1 + kb, Al1);
    gload16(Bg0 + kb, Bl0);
    gload16(Bg1 + kb, Bl1);
    __syncthreads();
    short8 af[4], bfr[4];
    #pragma unroll
    for (int m=0;m<4;m++) af[m]  = *(const short8*)(As + (wm + m*16 + lc)*32 + g*8);
    #pragma unroll
    for (int n=0;n<4;n++) bfr[n] = *(const short8*)(Bs + (wn + n*16 + lc)*32 + g*8);
    #pragma unroll
    for (int m=0;m<4;m++){
      #pragma unroll
      for (int n=0;n<4;n++)
        acc[m][n] = __builtin_amdgcn_mfma_f32_16x16x32_bf16(af[m], bfr[n], acc[m][n], 0, 0, 0);
    }
    __syncthreads();
  }

  #pragma unroll
  for (int n=0;n<4;n++){
    const int col = tn + wn + n*16 + lc;
    const float bv = bsel[col];
    #pragma unroll
    for (int m=0;m<4;m++){
      const int row = tm + wm + m*16 + g*4;
      #pragma unroll
      for (int r=0;r<4;r++)
        Cp[(size_t)(row + r)*N + col] = acc[m][n][r] + bv;
    }
  }
}

// ---------------- flash attention: KVBLK=128 joint softmax, V in 2x[64][64]
// (r14 exact — best verified: 96.7 us attn, 184.98 us total)
// 576 blocks = 32 bh x 18 q-tiles of 128 rows, XCD-chunked (4 bh/XCD).
// 8 waves x 64 lanes; wave w owns q-rows qt*128 + w*16 + [0,16).
// Per iteration: 128 kv with ONE joint softmax (one fmax tree over 32 regs,
// 2 shfls max + 2 sum, one defer check, one rescale, one barrier).
// K [128][64] swz dbuf (32K); V as TWO independent [64][64] swz tiles per
// buffer; Ps [8][1024] reused across halves (same-wave DS order).
__global__ __launch_bounds__(512) void k_attn(const short* __restrict__ Q,
                                              const short* __restrict__ Kg,
                                              const short* __restrict__ Vt,
                                              short* __restrict__ o1,
                                              short* __restrict__ o2){
  __shared__ __align__(16) short Kl[2][8192];
  __shared__ __align__(16) short Vl[2][2][4096];
  __shared__ __align__(16) short Ps[8][1024];
  const int t = threadIdx.x, w = t >> 6, l = t & 63;
  const int lc = l & 15, g = l >> 4;
  const int blk = blockIdx.x;
  const int ch = blk & 7, ii = blk >> 3;    // 576 = 8 * 72
  const int bh = ch * 4 + (ii / 18);        // 4 bh per XCD-chunk
  const int qt = ii % 18;
  const int b = bh >> 4, hh = bh & 15;
  const int q0 = qt * 128 + w * 16;
  const short* Qb = Q  + (size_t)bh * NT * HD;
  const short* Kb = Kg + (size_t)bh * NT * HD;
  const short* Vb = Vt + (size_t)bh * HD * NT;

  // Q fragment (B-operand): col q=lc, k-elems = head-dims g*8.. / +32
  short8 qf0 = *(const short8*)(Qb + (size_t)(q0 + lc) * HD + g*8);
  short8 qf1 = *(const short8*)(Qb + (size_t)(q0 + lc) * HD + g*8 + 32);

  // K staging role: row sr (0..127), chunks c0, c0+1 (32B per thread)
  const int sr = t >> 2, c0 = (t & 3) * 2;
  const short* Kgp = Kb + (size_t)sr * HD + c0 * 8;
  const int kw0 = swz(sr, c0), kw1 = swz(sr, c0 + 1);
  // V staging role: row vr (0..63), chunk vc0 (16B per thread per half-tile)
  const int vr = t >> 3, vc0 = t & 7;
  const short* Vgp = Vb + (size_t)vr * NT + vc0 * 8;   // + pi*128 + h*64
  const int vw0 = swz(vr, vc0);

  float mcur = -1e30f, lcur = 0.f;
  f32x4 oacc[4];
  #pragma unroll
  for (int j=0;j<4;j++){ oacc[j][0]=0.f; oacc[j][1]=0.f; oacc[j][2]=0.f; oacc[j][3]=0.f; }

  // prologue: stage pair 0 into buffer 0
  {
    short8 k0 = *(const short8*)(Kgp);
    short8 k1 = *(const short8*)(Kgp + 8);
    short8 v0 = *(const short8*)(Vgp);
    short8 v1 = *(const short8*)(Vgp + 64);
    *(short8*)&Kl[0][kw0] = k0;
    *(short8*)&Kl[0][kw1] = k1;
    *(short8*)&Vl[0][0][vw0] = v0;
    *(short8*)&Vl[0][1][vw0] = v1;
  }
  __syncthreads();

  for (int pi = 0; pi < 18; ++pi){
    const int cur = pi & 1;
    // issue next pair's global loads early (hide latency under compute)
    short8 kn0, kn1, vn0, vn1;
    if (pi < 17){
      const short* kp = Kgp + (size_t)(pi + 1) * 128 * HD;
      const short* vp = Vgp + (pi + 1) * 128;
      kn0 = *(const short8*)(kp);
      kn1 = *(const short8*)(kp + 8);
      vn0 = *(const short8*)(vp);
      vn1 = *(const short8*)(vp + 64);
    }
    // ---- S^T over 128 kv: s[j][r] = S[q=lc][kv = pi*128 + 16j + 4g + r] ----
    f32x4 s[8];
    __builtin_amdgcn_s_setprio(1);
    #pragma unroll
    for (int j=0;j<8;j++){
      const int row = j*16 + lc;
      short8 k0 = *(const short8*)(&Kl[cur][swz(row, g)]);
      short8 k1 = *(const short8*)(&Kl[cur][swz(row, g + 4)]);
      f32x4 a; a[0]=0.f; a[1]=0.f; a[2]=0.f; a[3]=0.f;
      a = __builtin_amdgcn_mfma_f32_16x16x32_bf16(k0, qf0, a, 0, 0, 0);
      a = __builtin_amdgcn_mfma_f32_16x16x32_bf16(k1, qf1, a, 0, 0, 0);
      s[j] = a;
    }
    __builtin_amdgcn_s_setprio(0);
    // ---- joint lane-local softmax over 128 kv for q-row lc ----
    float tj[8];
    #pragma unroll
    for (int j=0;j<8;j++)
      tj[j] = fmaxf(fmaxf(s[j][0], s[j][1]), fmaxf(s[j][2], s[j][3]));
    float tmx = fmaxf(fmaxf(fmaxf(tj[0], tj[1]), fmaxf(tj[2], tj[3])),
                      fmaxf(fmaxf(tj[4], tj[5]), fmaxf(tj[6], tj[7])));
    tmx = fmaxf(tmx, __shfl_xor(tmx, 16, 64));
    tmx = fmaxf(tmx, __shfl_xor(tmx, 32, 64));
    float mn = mcur;
    if (__any(tmx > mcur + RESCALE_THR)){
      mn = fmaxf(mcur, tmx);
      const float fsc = fexp2(mcur - mn);
      mcur = mn;
      lcur *= fsc;
      #pragma unroll
      for (int j=0;j<4;j++){
        oacc[j][0] *= fsc; oacc[j][1] *= fsc; oacc[j][2] *= fsc; oacc[j][3] *= fsc;
      }
    }
    // p = exp2(s - mn), in place
    #pragma unroll
    for (int j=0;j<8;j++){
      s[j][0] = fexp2(s[j][0] - mn);
      s[j][1] = fexp2(s[j][1] - mn);
      s[j][2] = fexp2(s[j][2] - mn);
      s[j][3] = fexp2(s[j][3] - mn);
    }
    float rs = 0.f;
    #pragma unroll
    for (int j=0;j<8;j++)
      rs += (s[j][0] + s[j][1]) + (s[j][2] + s[j][3]);
    rs += __shfl_xor(rs, 16, 64);
    rs += __shfl_xor(rs, 32, 64);
    lcur += rs;
    // ---- two 64-kv halves: P-write then PV (Ps reused; same-wave order) ----
    #pragma unroll
    for (int h=0;h<2;h++){
      #pragma unroll
      for (int j=0;j<4;j++){
        const int si = (lc << 6) + (((2*j + (g >> 1)) ^ (lc & 7)) << 3) + (g & 1) * 4;
        unsigned int* dst = (unsigned int*)&Ps[w][si];
        dst[0] = cvtpk2(s[h*4+j][0], s[h*4+j][1]);
        dst[1] = cvtpk2(s[h*4+j][2], s[h*4+j][3]);
      }
      #pragma unroll
      for (int kk=0;kk<2;kk++){
        short8 pa = *(const short8*)(&Ps[w][swz(lc, 4*kk + g)]);
        __builtin_amdgcn_s_setprio(1);
        #pragma unroll
        for (int jd=0;jd<4;jd++){
          short8 vb = *(const short8*)(&Vl[cur][h][swz(lc + 16*jd, 4*kk + g)]);
          oacc[jd] = __builtin_amdgcn_mfma_f32_16x16x32_bf16(vb, pa, oacc[jd], 0, 0, 0);
        }
        __builtin_amdgcn_s_setprio(0);
      }
    }
    // ---- write next pair into the other buffer, then sync ----
    if (pi < 17){
      *(short8*)&Kl[cur ^ 1][kw0] = kn0;
      *(short8*)&Kl[cur ^ 1][kw1] = kn1;
      *(short8*)&Vl[cur ^ 1][0][vw0] = vn0;
      *(short8*)&Vl[cur ^ 1][1][vw0] = vn1;
    }
    __syncthreads();
  }

  // ---- epilogue: normalize (lane-local) and write ----
  const float inv = 1.0f / lcur;
  const int qi = q0 + lc;
  short* obase = (qi < N1) ? (o1 + ((size_t)b * N1 + qi) * D_)
                           : (o2 + ((size_t)b * N2 + (qi - N1)) * D_);
  #pragma unroll
  for (int jd=0;jd<4;jd++){
    bf4 ov;
    #pragma unroll
    for (int r=0;r<4;r++) ov[r] = f2bf(oacc[jd][r] * inv);
    *(bf4*)(obase + hh*64 + 16*jd + 4*g) = ov;
  }
}

extern "C" void kernel_launch(void* const* d_in, const int* in_sizes, int n_in,
                              void* d_out, int out_size, void* d_ws, size_t ws_size,
                              hipStream_t stream){
  const float* x    = (const float*)d_in[0];
  const float* c    = (const float*)d_in[1];
  const float* fc   = (const float*)d_in[2];
  const float* fs   = (const float*)d_in[3];
  const float* Wq1  = (const float*)d_in[4];
  const float* bq1  = (const float*)d_in[5];
  const float* Wq2  = (const float*)d_in[6];
  const float* bq2  = (const float*)d_in[7];
  const float* qn1w = (const float*)d_in[8];
  const float* qn1b = (const float*)d_in[9];
  const float* kn1w = (const float*)d_in[10];
  const float* kn1b = (const float*)d_in[11];
  const float* qn2w = (const float*)d_in[12];
  const float* qn2b = (const float*)d_in[13];
  const float* kn2w = (const float*)d_in[14];
  const float* kn2b = (const float*)d_in[15];
  const float* Wp1  = (const float*)d_in[16];
  const float* bp1  = (const float*)d_in[17];
  const float* Wp2  = (const float*)d_in[18];
  const float* bp2  = (const float*)d_in[19];
  float* out = (float*)d_out;

  char* ws = (char*)d_ws;
  short* xb   = (short*)(ws);                       // 8,388,608 + cb 1,048,576 contiguous
  short* Wt1  = (short*)(ws + 9437184);             // 6,291,456
  short* Wt2  = (short*)(ws + 15728640);            // 6,291,456
  short* Wtp1 = (short*)(ws + 22020096);            // 2,097,152
  short* Wtp2 = (short*)(ws + 24117248);            // 2,097,152
  short* o1   = (short*)(ws + 26214400);            // 8,388,608 (+o2 1,048,576 contiguous)
  short* Vtb  = (short*)(ws + 26214400 + 9437184);  // 9,437,184
  short* Qb   = (short*)(ws + 54525952);            // 9,437,184
  short* Kb   = (short*)(ws + 63963136);            // 9,437,184

  k_cvt_all<<<2304, 256, 0, stream>>>(x, c, xb);
  k_transpose_w4<<<2048, 256, 0, stream>>>(Wq1, Wq2, Wp1, Wp2, Wt1, Wt2, Wtp1, Wtp2);

  // fused QKV GEMM + bias + LN + RoPE + split + V-transpose
  k_gemm_qkv<<<dim3(24,36), 256, 0, stream>>>(xb, Wt1, Wt2, bq1, bq2,
      qn1w, qn1b, kn1w, kn1b, qn2w, qn2b, kn2w, kn2b, fc, fs, Qb, Kb, Vtb);

  k_attn<<<576, 512, 0, stream>>>(Qb, Kb, Vtb, o1, o1 + 4194304);

  // fused projection GEMM: A = [o1; o2] (4608 x 1024), rows >= 4096 use Wtp2/bp2
  k_gemm_proj<<<dim3(8,36), 256, 0, stream>>>(o1, Wtp1, Wtp2, bp1, bp2, out, 1024, 1024, 4096);
}

// Round 18
// 180.698 us; speedup vs baseline: 1.2384x; 1.0228x over previous
//
#include <hip/hip_runtime.h>
#include <hip/hip_bf16.h>
#include <stdint.h>

typedef __attribute__((ext_vector_type(8))) short short8;
typedef __attribute__((ext_vector_type(4))) short bf4;
typedef __attribute__((ext_vector_type(4))) float f32x4;

#define B_ 2
#define N1 2048
#define N2 256
#define NT 2304
#define D_ 1024
#define H_ 16
#define HD 64
// attention scale folded into Q: hd^-0.5 * log2(e)
#define QSCALE 0.18033688011112042f
#define RESCALE_THR 8.0f

static __device__ __forceinline__ float bf2f(short s){
  union { unsigned int u; float f; } u;
  u.u = ((unsigned int)(unsigned short)s) << 16;
  return u.f;
}
// round-to-nearest-even f32 -> bf16 (finite inputs)
static __device__ __forceinline__ short f2bf(float f){
  union { float f; unsigned int u; } v; v.f = f;
  unsigned int u = v.u;
  unsigned int lsb = (u >> 16) & 1u;
  u += 0x7fffu + lsb;
  return (short)(u >> 16);
}
// packed f32x2 -> bf16x2 via compiler (v_cvt_pk_bf16_f32), RNE
static __device__ __forceinline__ unsigned int cvtpk2(float a, float b){
  union { __hip_bfloat162 h; unsigned int u; } cv;
  cv.h = __float22bfloat162_rn(make_float2(a, b));
  return cv.u;
}

static __device__ __forceinline__ float fexp2(float x){
#if __has_builtin(__builtin_amdgcn_exp2f)
  return __builtin_amdgcn_exp2f(x);
#else
  return exp2f(x);
#endif
}

static __device__ __forceinline__ void gload16(const void* g, void* l){
  __builtin_amdgcn_global_load_lds(
      (const __attribute__((address_space(1))) void*)g,
      (__attribute__((address_space(3))) void*)l, 16, 0, 0);
}

// swizzled short-index into a [rows][8 chunks of 8 shorts] LDS tile (row stride 64)
static __device__ __forceinline__ int swz(int row, int chunk){
  return (row << 6) + ((chunk ^ (row & 7)) << 3);
}

// ---------------- fp32 -> bf16 convert (x and c fused; outputs contiguous) --
__global__ __launch_bounds__(256) void k_cvt_all(const float* __restrict__ x,
                                                 const float* __restrict__ c,
                                                 short* __restrict__ out){
  int i = (blockIdx.x * 256 + threadIdx.x) * 8;
  const float* in = (i < 4194304) ? (x + i) : (c + (i - 4194304));
  float4 a = *(const float4*)(in);
  float4 b = *(const float4*)(in + 4);
  short8 o;
  o[0]=f2bf(a.x); o[1]=f2bf(a.y); o[2]=f2bf(a.z); o[3]=f2bf(a.w);
  o[4]=f2bf(b.x); o[5]=f2bf(b.y); o[6]=f2bf(b.z); o[7]=f2bf(b.w);
  *(short8*)(out + i) = o;
}

// ---------------- W (K x N, f32) -> Wt (N x K, bf16), 4 matrices fused -----
__global__ __launch_bounds__(256) void k_transpose_w4(
    const float* __restrict__ Wq1, const float* __restrict__ Wq2,
    const float* __restrict__ Wp1, const float* __restrict__ Wp2,
    short* __restrict__ Wt1, short* __restrict__ Wt2,
    short* __restrict__ Wtp1, short* __restrict__ Wtp2){
  const int id = blockIdx.x;
  const float* W; short* Wt; int N; int bx, by;
  if (id < 768)      { W = Wq1; Wt = Wt1;  N = 3072; bx = id % 48;          by = id / 48; }
  else if (id < 1536){ W = Wq2; Wt = Wt2;  N = 3072; bx = (id-768) % 48;    by = (id-768) / 48; }
  else if (id < 1792){ W = Wp1; Wt = Wtp1; N = 1024; bx = (id-1536) % 16;   by = (id-1536) / 16; }
  else               { W = Wp2; Wt = Wtp2; N = 1024; bx = (id-1792) % 16;   by = (id-1792) / 16; }
  const int K = 1024;
  __shared__ float tl[64][65];
  const int n0 = bx * 64, k0 = by * 64;
  const int t = threadIdx.x, r = t >> 2, c = (t & 3) * 16;
  const float* src = W + (size_t)(k0 + r) * N + n0 + c;
  #pragma unroll
  for (int i = 0; i < 16; i += 4){
    float4 v = *(const float4*)(src + i);
    tl[r][c+i] = v.x; tl[r][c+i+1] = v.y; tl[r][c+i+2] = v.z; tl[r][c+i+3] = v.w;
  }
  __syncthreads();
  short8 o0, o1;
  #pragma unroll
  for (int i = 0; i < 8; i++) o0[i] = f2bf(tl[c+i][r]);
  #pragma unroll
  for (int i = 0; i < 8; i++) o1[i] = f2bf(tl[c+8+i][r]);
  short* dst = Wt + (size_t)(n0 + r) * K + k0 + c;
  *(short8*)(dst)     = o0;
  *(short8*)(dst + 8) = o1;
}

// ---------------- fused QKV GEMM + bias + LN + RoPE + split + V-transpose --
// V is stored with the sigma/pi kv-permutation within each 64-token group:
// kv = 32K + 16s + 4g + r  ->  pos = 32K + 8g + 4s + r  (r preserved, so
// bf4 stores stay contiguous). k_attn's PV reads then consume P fragments
// that are fully lane-local (no Ps LDS buffer).
__global__ __launch_bounds__(256) void k_gemm_qkv(const short* __restrict__ A,
    const short* __restrict__ Bt, const short* __restrict__ Bt2,
    const float* __restrict__ bias, const float* __restrict__ bias2,
    const float* __restrict__ qn1w, const float* __restrict__ qn1b,
    const float* __restrict__ kn1w, const float* __restrict__ kn1b,
    const float* __restrict__ qn2w, const float* __restrict__ qn2b,
    const float* __restrict__ kn2w, const float* __restrict__ kn2b,
    const float* __restrict__ fcos, const float* __restrict__ fsin,
    short* __restrict__ Qo, short* __restrict__ Ko, short* __restrict__ Vto){
  __shared__ __align__(16) short As[128*32];
  __shared__ __align__(16) short Bs[128*32];
  const int t = threadIdx.x;
  const int w = t >> 6, l = t & 63;
  const int lc = l & 15, g = l >> 4;
  const int gx = gridDim.x;                 // 24
  const int nb = gx * gridDim.y;            // 864
  const int bid = blockIdx.y * gx + blockIdx.x;
  const int nbid = (bid & 7) * (nb >> 3) + (bid >> 3);
  const int tm = (nbid / gx) * 128, tn = (nbid % gx) * 128;
  const int wm = (w >> 1) * 64, wn = (w & 1) * 64;
  const int K = 1024;
  const bool s1 = (tm < 4096);

  const short* Bsel = s1 ? Bt : Bt2;
  const float* bsel = s1 ? bias : bias2;

  const int r0 = w*32 + (l >> 2);
  const int r1 = r0 + 16;
  const int cb = (l & 3) * 16;

  const char* Ag0 = (const char*)(A + (size_t)(tm + r0) * K) + cb;
  const char* Ag1 = (const char*)(A + (size_t)(tm + r1) * K) + cb;
  const char* Bg0 = (const char*)(Bsel + (size_t)(tn + r0) * K) + cb;
  const char* Bg1 = (const char*)(Bsel + (size_t)(tn + r1) * K) + cb;
  char* Al0 = (char*)As + (w*2  )*1024;
  char* Al1 = (char*)As + (w*2+1)*1024;
  char* Bl0 = (char*)Bs + (w*2  )*1024;
  char* Bl1 = (char*)Bs + (w*2+1)*1024;

  f32x4 acc[4][4];
  #pragma unroll
  for (int m=0;m<4;m++){
    #pragma unroll
    for (int n=0;n<4;n++){ acc[m][n][0]=0.f; acc[m][n][1]=0.f; acc[m][n][2]=0.f; acc[m][n][3]=0.f; }
  }

  for (int k0 = 0; k0 < K; k0 += 32){
    const int kb = k0 * 2;
    gload16(Ag0 + kb, Al0);
    gload16(Ag1 + kb, Al1);
    gload16(Bg0 + kb, Bl0);
    gload16(Bg1 + kb, Bl1);
    __syncthreads();
    short8 af[4], bfr[4];
    #pragma unroll
    for (int m=0;m<4;m++) af[m]  = *(const short8*)(As + (wm + m*16 + lc)*32 + g*8);
    #pragma unroll
    for (int n=0;n<4;n++) bfr[n] = *(const short8*)(Bs + (wn + n*16 + lc)*32 + g*8);
    #pragma unroll
    for (int m=0;m<4;m++){
      #pragma unroll
      for (int n=0;n<4;n++)
        acc[m][n] = __builtin_amdgcn_mfma_f32_16x16x32_bf16(af[m], bfr[n], acc[m][n], 0, 0, 0);
    }
    __syncthreads();
  }

  // ---- bias add (f32) ----
  #pragma unroll
  for (int n=0;n<4;n++){
    const float bv = bsel[tn + wn + n*16 + lc];
    #pragma unroll
    for (int m=0;m<4;m++){
      acc[m][n][0] += bv; acc[m][n][1] += bv; acc[m][n][2] += bv; acc[m][n][3] += bv;
    }
  }

  const int colbase = tn + wn;              // multiple of 64
  const int grp = colbase >> 10;            // 0=Q, 1=K, 2=V
  const int hh = (colbase & 1023) >> 6;     // head

  if (grp == 2){
    // ---- V: pass-through, transposed + pi-permuted store (b,h,64,NT) ----
    #pragma unroll
    for (int m=0;m<4;m++){
      const int row0 = tm + wm + m*16 + g*4;
      const int bb  = s1 ? (row0 >> 11) : ((row0 - 4096) >> 8);
      const int pos = s1 ? (row0 & 2047) : (2048 + ((row0 - 4096) & 255));
      // pi: within 64-group, (K32,s,gv) -> pos' = K32*32 + gv*8 + s*4
      const int local = pos & 63;
      const int posP = (pos & ~63) | ((local >> 5) << 5)
                     | (((local >> 2) & 3) << 3) | (((local >> 4) & 1) << 2);
      short* vbase = Vto + (size_t)(bb*16 + hh) * 64 * NT + posP;
      #pragma unroll
      for (int n=0;n<4;n++){
        const int d = n*16 + lc;
        bf4 ov;
        #pragma unroll
        for (int r=0;r<4;r++) ov[r] = f2bf(acc[m][n][r]);
        *(bf4*)(vbase + (size_t)d * NT) = ov;
      }
    }
    return;
  }

  // ---- Q/K: LN (+RoPE for stream1), write (b,h,NT,64) ----
  const float* lnw = (grp == 0) ? (s1 ? qn1w : qn2w) : (s1 ? kn1w : kn2w);
  const float* lnb = (grp == 0) ? (s1 ? qn1b : qn2b) : (s1 ? kn1b : kn2b);
  short* outp = (grp == 0) ? Qo : Ko;
  float wv_[4], bv_[4];
  #pragma unroll
  for (int n=0;n<4;n++){ wv_[n] = lnw[n*16 + lc]; bv_[n] = lnb[n*16 + lc]; }

  #pragma unroll
  for (int m=0;m<4;m++){
    float mu[4], rv[4];
    #pragma unroll
    for (int r=0;r<4;r++){
      float s  = (acc[m][0][r] + acc[m][1][r]) + (acc[m][2][r] + acc[m][3][r]);
      float sq = (acc[m][0][r]*acc[m][0][r] + acc[m][1][r]*acc[m][1][r])
               + (acc[m][2][r]*acc[m][2][r] + acc[m][3][r]*acc[m][3][r]);
      s  += __shfl_xor(s, 1, 64);  sq += __shfl_xor(sq, 1, 64);
      s  += __shfl_xor(s, 2, 64);  sq += __shfl_xor(sq, 2, 64);
      s  += __shfl_xor(s, 4, 64);  sq += __shfl_xor(sq, 4, 64);
      s  += __shfl_xor(s, 8, 64);  sq += __shfl_xor(sq, 8, 64);
      mu[r] = s * (1.f/64.f);
      const float var = sq * (1.f/64.f) - mu[r]*mu[r];
      rv[r] = rsqrtf(var + 1e-5f);
    }
    const int row0 = tm + wm + m*16 + g*4;
    const int bb  = s1 ? (row0 >> 11) : ((row0 - 4096) >> 8);
    const int pos0 = s1 ? (row0 & 2047) : (2048 + ((row0 - 4096) & 255));
    short* obase = outp + ((size_t)(bb*16 + hh) * NT + pos0) * 64;
    #pragma unroll
    for (int n=0;n<4;n++){
      float xh[4];
      #pragma unroll
      for (int r=0;r<4;r++) xh[r] = (acc[m][n][r] - mu[r]) * rv[r] * wv_[n] + bv_[n];
      if (s1){
        #pragma unroll
        for (int r=0;r<4;r++){
          const size_t fi = (size_t)(pos0 + r) * 32 + n*8 + (lc >> 1);
          const float cv = fcos[fi];
          const float sv = fsin[fi];
          const float p = __shfl_xor(xh[r], 1, 64);
          xh[r] = (lc & 1) ? (p*sv + xh[r]*cv) : (xh[r]*cv - p*sv);
        }
      }
      if (grp == 0){
        #pragma unroll
        for (int r=0;r<4;r++) xh[r] *= QSCALE;
      }
      const int d = n*16 + lc;
      #pragma unroll
      for (int r=0;r<4;r++) obase[(size_t)r * 64 + d] = f2bf(xh[r]);
    }
  }
}

// ---------------- proj GEMM: C[M,N] = A[M,K] * Bt[N,K]^T + bias (f32 out) --
__global__ __launch_bounds__(256) void k_gemm_proj(const short* __restrict__ A,
                                                   const short* __restrict__ Bt,
                                                   const short* __restrict__ Bt2,
                                                   const float* __restrict__ bias,
                                                   const float* __restrict__ bias2,
                                                   float* __restrict__ Cp,
                                                   int N, int K, int Msplit){
  __shared__ __align__(16) short As[128*32];
  __shared__ __align__(16) short Bs[128*32];
  const int t = threadIdx.x;
  const int w = t >> 6, l = t & 63;
  const int lc = l & 15, g = l >> 4;
  const int gx = gridDim.x;
  const int nb = gx * gridDim.y;
  const int bid = blockIdx.y * gx + blockIdx.x;
  const int nbid = (bid & 7) * (nb >> 3) + (bid >> 3);
  const int tm = (nbid / gx) * 128, tn = (nbid % gx) * 128;
  const int wm = (w >> 1) * 64, wn = (w & 1) * 64;

  const short* Bsel = (tm < Msplit) ? Bt : Bt2;
  const float* bsel = (tm < Msplit) ? bias : bias2;

  const int r0 = w*32 + (l >> 2);
  const int r1 = r0 + 16;
  const int cb = (l & 3) * 16;

  const char* Ag0 = (const char*)(A + (size_t)(tm + r0) * K) + cb;
  const char* Ag1 = (const char*)(A + (size_t)(tm + r1) * K) + cb;
  const char* Bg0 = (const char*)(Bsel + (size_t)(tn + r0) * K) + cb;
  const char* Bg1 = (const char*)(Bsel + (size_t)(tn + r1) * K) + cb;
  char* Al0 = (char*)As + (w*2  )*1024;
  char* Al1 = (char*)As + (w*2+1)*1024;
  char* Bl0 = (char*)Bs + (w*2  )*1024;
  char* Bl1 = (char*)Bs + (w*2+1)*1024;

  f32x4 acc[4][4];
  #pragma unroll
  for (int m=0;m<4;m++){
    #pragma unroll
    for (int n=0;n<4;n++){ acc[m][n][0]=0.f; acc[m][n][1]=0.f; acc[m][n][2]=0.f; acc[m][n][3]=0.f; }
  }

  for (int k0 = 0; k0 < K; k0 += 32){
    const int kb = k0 * 2;
    gload16(Ag0 + kb, Al0);
    gload16(Ag1 + kb, Al1);
    gload16(Bg0 + kb, Bl0);
    gload16(Bg1 + kb, Bl1);
    __syncthreads();
    short8 af[4], bfr[4];
    #pragma unroll
    for (int m=0;m<4;m++) af[m]  = *(const short8*)(As + (wm + m*16 + lc)*32 + g*8);
    #pragma unroll
    for (int n=0;n<4;n++) bfr[n] = *(const short8*)(Bs + (wn + n*16 + lc)*32 + g*8);
    #pragma unroll
    for (int m=0;m<4;m++){
      #pragma unroll
      for (int n=0;n<4;n++)
        acc[m][n] = __builtin_amdgcn_mfma_f32_16x16x32_bf16(af[m], bfr[n], acc[m][n], 0, 0, 0);
    }
    __syncthreads();
  }

  #pragma unroll
  for (int n=0;n<4;n++){
    const int col = tn + wn + n*16 + lc;
    const float bv = bsel[col];
    #pragma unroll
    for (int m=0;m<4;m++){
      const int row = tm + wm + m*16 + g*4;
      #pragma unroll
      for (int r=0;r<4;r++)
        Cp[(size_t)(row + r)*N + col] = acc[m][n][r] + bv;
    }
  }
}

// ---------------- flash attention: KVBLK=128, lane-local P (no Ps LDS) ----
// r14 structure with the sigma-permuted PV: the P B-fragment is built from
// the lane's OWN softmax registers (4 cvtpk2, zero LDS, zero cross-lane);
// V was pre-permuted at the producer so V reads are byte-identical to r14.
// 576 blocks = 32 bh x 18 q-tiles of 128 rows, XCD-chunked (4 bh/XCD).
// 8 waves x 64 lanes; wave w owns q-rows qt*128 + w*16 + [0,16).
// K [128][64] swz dbuf (32K); V as TWO [64][64] swz tiles per buffer (32K).
__global__ __launch_bounds__(512) void k_attn(const short* __restrict__ Q,
                                              const short* __restrict__ Kg,
                                              const short* __restrict__ Vt,
                                              short* __restrict__ o1,
                                              short* __restrict__ o2){
  __shared__ __align__(16) short Kl[2][8192];
  __shared__ __align__(16) short Vl[2][2][4096];
  const int t = threadIdx.x, w = t >> 6, l = t & 63;
  const int lc = l & 15, g = l >> 4;
  const int blk = blockIdx.x;
  const int ch = blk & 7, ii = blk >> 3;    // 576 = 8 * 72
  const int bh = ch * 4 + (ii / 18);        // 4 bh per XCD-chunk
  const int qt = ii % 18;
  const int b = bh >> 4, hh = bh & 15;
  const int q0 = qt * 128 + w * 16;
  const short* Qb = Q  + (size_t)bh * NT * HD;
  const short* Kb = Kg + (size_t)bh * NT * HD;
  const short* Vb = Vt + (size_t)bh * HD * NT;

  // Q fragment (B-operand): col q=lc, k-elems = head-dims g*8.. / +32
  short8 qf0 = *(const short8*)(Qb + (size_t)(q0 + lc) * HD + g*8);
  short8 qf1 = *(const short8*)(Qb + (size_t)(q0 + lc) * HD + g*8 + 32);

  // K staging role: row sr (0..127), chunks c0, c0+1 (32B per thread)
  const int sr = t >> 2, c0 = (t & 3) * 2;
  const short* Kgp = Kb + (size_t)sr * HD + c0 * 8;
  const int kw0 = swz(sr, c0), kw1 = swz(sr, c0 + 1);
  // V staging role: row vr (0..63), chunk vc0 (16B per thread per half-tile)
  const int vr = t >> 3, vc0 = t & 7;
  const short* Vgp = Vb + (size_t)vr * NT + vc0 * 8;   // + pi*128 + h*64
  const int vw0 = swz(vr, vc0);

  float mcur = -1e30f, lcur = 0.f;
  f32x4 oacc[4];
  #pragma unroll
  for (int j=0;j<4;j++){ oacc[j][0]=0.f; oacc[j][1]=0.f; oacc[j][2]=0.f; oacc[j][3]=0.f; }

  // prologue: stage pair 0 into buffer 0
  {
    short8 k0 = *(const short8*)(Kgp);
    short8 k1 = *(const short8*)(Kgp + 8);
    short8 v0 = *(const short8*)(Vgp);
    short8 v1 = *(const short8*)(Vgp + 64);
    *(short8*)&Kl[0][kw0] = k0;
    *(short8*)&Kl[0][kw1] = k1;
    *(short8*)&Vl[0][0][vw0] = v0;
    *(short8*)&Vl[0][1][vw0] = v1;
  }
  __syncthreads();

  for (int pi = 0; pi < 18; ++pi){
    const int cur = pi & 1;
    // issue next pair's global loads early (hide latency under compute)
    short8 kn0, kn1, vn0, vn1;
    if (pi < 17){
      const short* kp = Kgp + (size_t)(pi + 1) * 128 * HD;
      const short* vp = Vgp + (pi + 1) * 128;
      kn0 = *(const short8*)(kp);
      kn1 = *(const short8*)(kp + 8);
      vn0 = *(const short8*)(vp);
      vn1 = *(const short8*)(vp + 64);
    }
    // ---- S^T over 128 kv: s[j][r] = S[q=lc][kv = pi*128 + 16j + 4g + r] ----
    f32x4 s[8];
    __builtin_amdgcn_s_setprio(1);
    #pragma unroll
    for (int j=0;j<8;j++){
      const int row = j*16 + lc;
      short8 k0 = *(const short8*)(&Kl[cur][swz(row, g)]);
      short8 k1 = *(const short8*)(&Kl[cur][swz(row, g + 4)]);
      f32x4 a; a[0]=0.f; a[1]=0.f; a[2]=0.f; a[3]=0.f;
      a = __builtin_amdgcn_mfma_f32_16x16x32_bf16(k0, qf0, a, 0, 0, 0);
      a = __builtin_amdgcn_mfma_f32_16x16x32_bf16(k1, qf1, a, 0, 0, 0);
      s[j] = a;
    }
    __builtin_amdgcn_s_setprio(0);
    // ---- joint lane-local softmax over 128 kv for q-row lc ----
    float tj[8];
    #pragma unroll
    for (int j=0;j<8;j++)
      tj[j] = fmaxf(fmaxf(s[j][0], s[j][1]), fmaxf(s[j][2], s[j][3]));
    float tmx = fmaxf(fmaxf(fmaxf(tj[0], tj[1]), fmaxf(tj[2], tj[3])),
                      fmaxf(fmaxf(tj[4], tj[5]), fmaxf(tj[6], tj[7])));
    tmx = fmaxf(tmx, __shfl_xor(tmx, 16, 64));
    tmx = fmaxf(tmx, __shfl_xor(tmx, 32, 64));
    float mn = mcur;
    if (__any(tmx > mcur + RESCALE_THR)){
      mn = fmaxf(mcur, tmx);
      const float fsc = fexp2(mcur - mn);
      mcur = mn;
      lcur *= fsc;
      #pragma unroll
      for (int j=0;j<4;j++){
        oacc[j][0] *= fsc; oacc[j][1] *= fsc; oacc[j][2] *= fsc; oacc[j][3] *= fsc;
      }
    }
    // p = exp2(s - mn), in place
    #pragma unroll
    for (int j=0;j<8;j++){
      s[j][0] = fexp2(s[j][0] - mn);
      s[j][1] = fexp2(s[j][1] - mn);
      s[j][2] = fexp2(s[j][2] - mn);
      s[j][3] = fexp2(s[j][3] - mn);
    }
    float rs = 0.f;
    #pragma unroll
    for (int j=0;j<8;j++)
      rs += (s[j][0] + s[j][1]) + (s[j][2] + s[j][3]);
    rs += __shfl_xor(rs, 16, 64);
    rs += __shfl_xor(rs, 32, 64);
    lcur += rs;
    // ---- PV: sigma-permuted slots -> P fragment is fully lane-local ----
    // slot (g,e) of mfma kk holds kv = 32kk + 16(e>>2) + 4g + (e&3)
    //  => B-operand = lane's own p[j0..j0+1][0..3], j0 = 4h + 2kk.
    //  V was stored pi-permuted at the producer, so V reads are r14-exact.
    #pragma unroll
    for (int h=0;h<2;h++){
      #pragma unroll
      for (int kk=0;kk<2;kk++){
        const int j0 = h*4 + kk*2;
        union { unsigned int u[4]; short8 s8; } pf;
        pf.u[0] = cvtpk2(s[j0  ][0], s[j0  ][1]);
        pf.u[1] = cvtpk2(s[j0  ][2], s[j0  ][3]);
        pf.u[2] = cvtpk2(s[j0+1][0], s[j0+1][1]);
        pf.u[3] = cvtpk2(s[j0+1][2], s[j0+1][3]);
        __builtin_amdgcn_s_setprio(1);
        #pragma unroll
        for (int jd=0;jd<4;jd++){
          short8 vb = *(const short8*)(&Vl[cur][h][swz(lc + 16*jd, 4*kk + g)]);
          oacc[jd] = __builtin_amdgcn_mfma_f32_16x16x32_bf16(vb, pf.s8, oacc[jd], 0, 0, 0);
        }
        __builtin_amdgcn_s_setprio(0);
      }
    }
    // ---- write next pair into the other buffer, then sync ----
    if (pi < 17){
      *(short8*)&Kl[cur ^ 1][kw0] = kn0;
      *(short8*)&Kl[cur ^ 1][kw1] = kn1;
      *(short8*)&Vl[cur ^ 1][0][vw0] = vn0;
      *(short8*)&Vl[cur ^ 1][1][vw0] = vn1;
    }
    __syncthreads();
  }

  // ---- epilogue: normalize (lane-local) and write ----
  const float inv = 1.0f / lcur;
  const int qi = q0 + lc;
  short* obase = (qi < N1) ? (o1 + ((size_t)b * N1 + qi) * D_)
                           : (o2 + ((size_t)b * N2 + (qi - N1)) * D_);
  #pragma unroll
  for (int jd=0;jd<4;jd++){
    bf4 ov;
    #pragma unroll
    for (int r=0;r<4;r++) ov[r] = f2bf(oacc[jd][r] * inv);
    *(bf4*)(obase + hh*64 + 16*jd + 4*g) = ov;
  }
}

extern "C" void kernel_launch(void* const* d_in, const int* in_sizes, int n_in,
                              void* d_out, int out_size, void* d_ws, size_t ws_size,
                              hipStream_t stream){
  const float* x    = (const float*)d_in[0];
  const float* c    = (const float*)d_in[1];
  const float* fc   = (const float*)d_in[2];
  const float* fs   = (const float*)d_in[3];
  const float* Wq1  = (const float*)d_in[4];
  const float* bq1  = (const float*)d_in[5];
  const float* Wq2  = (const float*)d_in[6];
  const float* bq2  = (const float*)d_in[7];
  const float* qn1w = (const float*)d_in[8];
  const float* qn1b = (const float*)d_in[9];
  const float* kn1w = (const float*)d_in[10];
  const float* kn1b = (const float*)d_in[11];
  const float* qn2w = (const float*)d_in[12];
  const float* qn2b = (const float*)d_in[13];
  const float* kn2w = (const float*)d_in[14];
  const float* kn2b = (const float*)d_in[15];
  const float* Wp1  = (const float*)d_in[16];
  const float* bp1  = (const float*)d_in[17];
  const float* Wp2  = (const float*)d_in[18];
  const float* bp2  = (const float*)d_in[19];
  float* out = (float*)d_out;

  char* ws = (char*)d_ws;
  short* xb   = (short*)(ws);                       // 8,388,608 + cb 1,048,576 contiguous
  short* Wt1  = (short*)(ws + 9437184);             // 6,291,456
  short* Wt2  = (short*)(ws + 15728640);            // 6,291,456
  short* Wtp1 = (short*)(ws + 22020096);            // 2,097,152
  short* Wtp2 = (short*)(ws + 24117248);            // 2,097,152
  short* o1   = (short*)(ws + 26214400);            // 8,388,608 (+o2 1,048,576 contiguous)
  short* Vtb  = (short*)(ws + 26214400 + 9437184);  // 9,437,184
  short* Qb   = (short*)(ws + 54525952);            // 9,437,184
  short* Kb   = (short*)(ws + 63963136);            // 9,437,184

  k_cvt_all<<<2304, 256, 0, stream>>>(x, c, xb);
  k_transpose_w4<<<2048, 256, 0, stream>>>(Wq1, Wq2, Wp1, Wp2, Wt1, Wt2, Wtp1, Wtp2);

  // fused QKV GEMM + bias + LN + RoPE + split + V-transpose (pi-permuted)
  k_gemm_qkv<<<dim3(24,36), 256, 0, stream>>>(xb, Wt1, Wt2, bq1, bq2,
      qn1w, qn1b, kn1w, kn1b, qn2w, qn2b, kn2w, kn2b, fc, fs, Qb, Kb, Vtb);

  k_attn<<<576, 512, 0, stream>>>(Qb, Kb, Vtb, o1, o1 + 4194304);

  // fused projection GEMM: A = [o1; o2] (4608 x 1024), rows >= 4096 use Wtp2/bp2
  k_gemm_proj<<<dim3(8,36), 256, 0, stream>>>(o1, Wtp1, Wtp2, bp1, bp2, out, 1024, 1024, 4096);
}

// Round 19
// 177.218 us; speedup vs baseline: 1.2627x; 1.0196x over previous
//
#include <hip/hip_runtime.h>
#include <hip/hip_bf16.h>
#include <stdint.h>

typedef __attribute__((ext_vector_type(8))) short short8;
typedef __attribute__((ext_vector_type(4))) short bf4;
typedef __attribute__((ext_vector_type(4))) float f32x4;

#define B_ 2
#define N1 2048
#define N2 256
#define NT 2304
#define D_ 1024
#define H_ 16
#define HD 64
// attention scale folded into Q: hd^-0.5 * log2(e)
#define QSCALE 0.18033688011112042f
#define RESCALE_THR 8.0f

static __device__ __forceinline__ float bf2f(short s){
  union { unsigned int u; float f; } u;
  u.u = ((unsigned int)(unsigned short)s) << 16;
  return u.f;
}
// round-to-nearest-even f32 -> bf16 (finite inputs)
static __device__ __forceinline__ short f2bf(float f){
  union { float f; unsigned int u; } v; v.f = f;
  unsigned int u = v.u;
  unsigned int lsb = (u >> 16) & 1u;
  u += 0x7fffu + lsb;
  return (short)(u >> 16);
}
// packed f32x2 -> bf16x2 via compiler (v_cvt_pk_bf16_f32), RNE
static __device__ __forceinline__ unsigned int cvtpk2(float a, float b){
  union { __hip_bfloat162 h; unsigned int u; } cv;
  cv.h = __float22bfloat162_rn(make_float2(a, b));
  return cv.u;
}

static __device__ __forceinline__ float fexp2(float x){
#if __has_builtin(__builtin_amdgcn_exp2f)
  return __builtin_amdgcn_exp2f(x);
#else
  return exp2f(x);
#endif
}

static __device__ __forceinline__ void gload16(const void* g, void* l){
  __builtin_amdgcn_global_load_lds(
      (const __attribute__((address_space(1))) void*)g,
      (__attribute__((address_space(3))) void*)l, 16, 0, 0);
}

// swizzled short-index into a [rows][8 chunks of 8 shorts] LDS tile (row stride 64)
static __device__ __forceinline__ int swz(int row, int chunk){
  return (row << 6) + ((chunk ^ (row & 7)) << 3);
}

// ---------------- fp32 -> bf16 convert (x and c fused; outputs contiguous) --
__global__ __launch_bounds__(256) void k_cvt_all(const float* __restrict__ x,
                                                 const float* __restrict__ c,
                                                 short* __restrict__ out){
  int i = (blockIdx.x * 256 + threadIdx.x) * 8;
  const float* in = (i < 4194304) ? (x + i) : (c + (i - 4194304));
  float4 a = *(const float4*)(in);
  float4 b = *(const float4*)(in + 4);
  short8 o;
  o[0]=f2bf(a.x); o[1]=f2bf(a.y); o[2]=f2bf(a.z); o[3]=f2bf(a.w);
  o[4]=f2bf(b.x); o[5]=f2bf(b.y); o[6]=f2bf(b.z); o[7]=f2bf(b.w);
  *(short8*)(out + i) = o;
}

// ---------------- W (K x N, f32) -> Wt (N x K, bf16), 4 matrices fused -----
__global__ __launch_bounds__(256) void k_transpose_w4(
    const float* __restrict__ Wq1, const float* __restrict__ Wq2,
    const float* __restrict__ Wp1, const float* __restrict__ Wp2,
    short* __restrict__ Wt1, short* __restrict__ Wt2,
    short* __restrict__ Wtp1, short* __restrict__ Wtp2){
  const int id = blockIdx.x;
  const float* W; short* Wt; int N; int bx, by;
  if (id < 768)      { W = Wq1; Wt = Wt1;  N = 3072; bx = id % 48;          by = id / 48; }
  else if (id < 1536){ W = Wq2; Wt = Wt2;  N = 3072; bx = (id-768) % 48;    by = (id-768) / 48; }
  else if (id < 1792){ W = Wp1; Wt = Wtp1; N = 1024; bx = (id-1536) % 16;   by = (id-1536) / 16; }
  else               { W = Wp2; Wt = Wtp2; N = 1024; bx = (id-1792) % 16;   by = (id-1792) / 16; }
  const int K = 1024;
  __shared__ float tl[64][65];
  const int n0 = bx * 64, k0 = by * 64;
  const int t = threadIdx.x, r = t >> 2, c = (t & 3) * 16;
  const float* src = W + (size_t)(k0 + r) * N + n0 + c;
  #pragma unroll
  for (int i = 0; i < 16; i += 4){
    float4 v = *(const float4*)(src + i);
    tl[r][c+i] = v.x; tl[r][c+i+1] = v.y; tl[r][c+i+2] = v.z; tl[r][c+i+3] = v.w;
  }
  __syncthreads();
  short8 o0, o1;
  #pragma unroll
  for (int i = 0; i < 8; i++) o0[i] = f2bf(tl[c+i][r]);
  #pragma unroll
  for (int i = 0; i < 8; i++) o1[i] = f2bf(tl[c+8+i][r]);
  short* dst = Wt + (size_t)(n0 + r) * K + k0 + c;
  *(short8*)(dst)     = o0;
  *(short8*)(dst + 8) = o1;
}

// ---------------- fused QKV GEMM + bias + LN + RoPE + split + V-transpose --
// V is stored with the sigma/pi kv-permutation within each 64-token group:
// kv = 32K + 16s + 4g + r  ->  pos = 32K + 8g + 4s + r  (r preserved, so
// bf4 stores stay contiguous). k_attn's PV reads then consume P fragments
// that are fully lane-local (no Ps LDS buffer).
__global__ __launch_bounds__(256) void k_gemm_qkv(const short* __restrict__ A,
    const short* __restrict__ Bt, const short* __restrict__ Bt2,
    const float* __restrict__ bias, const float* __restrict__ bias2,
    const float* __restrict__ qn1w, const float* __restrict__ qn1b,
    const float* __restrict__ kn1w, const float* __restrict__ kn1b,
    const float* __restrict__ qn2w, const float* __restrict__ qn2b,
    const float* __restrict__ kn2w, const float* __restrict__ kn2b,
    const float* __restrict__ fcos, const float* __restrict__ fsin,
    short* __restrict__ Qo, short* __restrict__ Ko, short* __restrict__ Vto){
  __shared__ __align__(16) short As[128*32];
  __shared__ __align__(16) short Bs[128*32];
  const int t = threadIdx.x;
  const int w = t >> 6, l = t & 63;
  const int lc = l & 15, g = l >> 4;
  const int gx = gridDim.x;                 // 24
  const int nb = gx * gridDim.y;            // 864
  const int bid = blockIdx.y * gx + blockIdx.x;
  const int nbid = (bid & 7) * (nb >> 3) + (bid >> 3);
  const int tm = (nbid / gx) * 128, tn = (nbid % gx) * 128;
  const int wm = (w >> 1) * 64, wn = (w & 1) * 64;
  const int K = 1024;
  const bool s1 = (tm < 4096);

  const short* Bsel = s1 ? Bt : Bt2;
  const float* bsel = s1 ? bias : bias2;

  const int r0 = w*32 + (l >> 2);
  const int r1 = r0 + 16;
  const int cb = (l & 3) * 16;

  const char* Ag0 = (const char*)(A + (size_t)(tm + r0) * K) + cb;
  const char* Ag1 = (const char*)(A + (size_t)(tm + r1) * K) + cb;
  const char* Bg0 = (const char*)(Bsel + (size_t)(tn + r0) * K) + cb;
  const char* Bg1 = (const char*)(Bsel + (size_t)(tn + r1) * K) + cb;
  char* Al0 = (char*)As + (w*2  )*1024;
  char* Al1 = (char*)As + (w*2+1)*1024;
  char* Bl0 = (char*)Bs + (w*2  )*1024;
  char* Bl1 = (char*)Bs + (w*2+1)*1024;

  f32x4 acc[4][4];
  #pragma unroll
  for (int m=0;m<4;m++){
    #pragma unroll
    for (int n=0;n<4;n++){ acc[m][n][0]=0.f; acc[m][n][1]=0.f; acc[m][n][2]=0.f; acc[m][n][3]=0.f; }
  }

  for (int k0 = 0; k0 < K; k0 += 32){
    const int kb = k0 * 2;
    gload16(Ag0 + kb, Al0);
    gload16(Ag1 + kb, Al1);
    gload16(Bg0 + kb, Bl0);
    gload16(Bg1 + kb, Bl1);
    __syncthreads();
    short8 af[4], bfr[4];
    #pragma unroll
    for (int m=0;m<4;m++) af[m]  = *(const short8*)(As + (wm + m*16 + lc)*32 + g*8);
    #pragma unroll
    for (int n=0;n<4;n++) bfr[n] = *(const short8*)(Bs + (wn + n*16 + lc)*32 + g*8);
    #pragma unroll
    for (int m=0;m<4;m++){
      #pragma unroll
      for (int n=0;n<4;n++)
        acc[m][n] = __builtin_amdgcn_mfma_f32_16x16x32_bf16(af[m], bfr[n], acc[m][n], 0, 0, 0);
    }
    __syncthreads();
  }

  // ---- bias add (f32) ----
  #pragma unroll
  for (int n=0;n<4;n++){
    const float bv = bsel[tn + wn + n*16 + lc];
    #pragma unroll
    for (int m=0;m<4;m++){
      acc[m][n][0] += bv; acc[m][n][1] += bv; acc[m][n][2] += bv; acc[m][n][3] += bv;
    }
  }

  const int colbase = tn + wn;              // multiple of 64
  const int grp = colbase >> 10;            // 0=Q, 1=K, 2=V
  const int hh = (colbase & 1023) >> 6;     // head

  if (grp == 2){
    // ---- V: pass-through, transposed + pi-permuted store (b,h,64,NT) ----
    #pragma unroll
    for (int m=0;m<4;m++){
      const int row0 = tm + wm + m*16 + g*4;
      const int bb  = s1 ? (row0 >> 11) : ((row0 - 4096) >> 8);
      const int pos = s1 ? (row0 & 2047) : (2048 + ((row0 - 4096) & 255));
      // pi: within 64-group, (K32,s,gv) -> pos' = K32*32 + gv*8 + s*4
      const int local = pos & 63;
      const int posP = (pos & ~63) | ((local >> 5) << 5)
                     | (((local >> 2) & 3) << 3) | (((local >> 4) & 1) << 2);
      short* vbase = Vto + (size_t)(bb*16 + hh) * 64 * NT + posP;
      #pragma unroll
      for (int n=0;n<4;n++){
        const int d = n*16 + lc;
        bf4 ov;
        #pragma unroll
        for (int r=0;r<4;r++) ov[r] = f2bf(acc[m][n][r]);
        *(bf4*)(vbase + (size_t)d * NT) = ov;
      }
    }
    return;
  }

  // ---- Q/K: LN (+RoPE for stream1), write (b,h,NT,64) ----
  const float* lnw = (grp == 0) ? (s1 ? qn1w : qn2w) : (s1 ? kn1w : kn2w);
  const float* lnb = (grp == 0) ? (s1 ? qn1b : qn2b) : (s1 ? kn1b : kn2b);
  short* outp = (grp == 0) ? Qo : Ko;
  float wv_[4], bv_[4];
  #pragma unroll
  for (int n=0;n<4;n++){ wv_[n] = lnw[n*16 + lc]; bv_[n] = lnb[n*16 + lc]; }

  #pragma unroll
  for (int m=0;m<4;m++){
    float mu[4], rv[4];
    #pragma unroll
    for (int r=0;r<4;r++){
      float s  = (acc[m][0][r] + acc[m][1][r]) + (acc[m][2][r] + acc[m][3][r]);
      float sq = (acc[m][0][r]*acc[m][0][r] + acc[m][1][r]*acc[m][1][r])
               + (acc[m][2][r]*acc[m][2][r] + acc[m][3][r]*acc[m][3][r]);
      s  += __shfl_xor(s, 1, 64);  sq += __shfl_xor(sq, 1, 64);
      s  += __shfl_xor(s, 2, 64);  sq += __shfl_xor(sq, 2, 64);
      s  += __shfl_xor(s, 4, 64);  sq += __shfl_xor(sq, 4, 64);
      s  += __shfl_xor(s, 8, 64);  sq += __shfl_xor(sq, 8, 64);
      mu[r] = s * (1.f/64.f);
      const float var = sq * (1.f/64.f) - mu[r]*mu[r];
      rv[r] = rsqrtf(var + 1e-5f);
    }
    const int row0 = tm + wm + m*16 + g*4;
    const int bb  = s1 ? (row0 >> 11) : ((row0 - 4096) >> 8);
    const int pos0 = s1 ? (row0 & 2047) : (2048 + ((row0 - 4096) & 255));
    short* obase = outp + ((size_t)(bb*16 + hh) * NT + pos0) * 64;
    #pragma unroll
    for (int n=0;n<4;n++){
      float xh[4];
      #pragma unroll
      for (int r=0;r<4;r++) xh[r] = (acc[m][n][r] - mu[r]) * rv[r] * wv_[n] + bv_[n];
      if (s1){
        #pragma unroll
        for (int r=0;r<4;r++){
          const size_t fi = (size_t)(pos0 + r) * 32 + n*8 + (lc >> 1);
          const float cv = fcos[fi];
          const float sv = fsin[fi];
          const float p = __shfl_xor(xh[r], 1, 64);
          xh[r] = (lc & 1) ? (p*sv + xh[r]*cv) : (xh[r]*cv - p*sv);
        }
      }
      if (grp == 0){
        #pragma unroll
        for (int r=0;r<4;r++) xh[r] *= QSCALE;
      }
      const int d = n*16 + lc;
      #pragma unroll
      for (int r=0;r<4;r++) obase[(size_t)r * 64 + d] = f2bf(xh[r]);
    }
  }
}

// ---------------- proj GEMM: C[M,N] = A[M,K] * Bt[N,K]^T + bias (f32 out) --
__global__ __launch_bounds__(256) void k_gemm_proj(const short* __restrict__ A,
                                                   const short* __restrict__ Bt,
                                                   const short* __restrict__ Bt2,
                                                   const float* __restrict__ bias,
                                                   const float* __restrict__ bias2,
                                                   float* __restrict__ Cp,
                                                   int N, int K, int Msplit){
  __shared__ __align__(16) short As[128*32];
  __shared__ __align__(16) short Bs[128*32];
  const int t = threadIdx.x;
  const int w = t >> 6, l = t & 63;
  const int lc = l & 15, g = l >> 4;
  const int gx = gridDim.x;
  const int nb = gx * gridDim.y;
  const int bid = blockIdx.y * gx + blockIdx.x;
  const int nbid = (bid & 7) * (nb >> 3) + (bid >> 3);
  const int tm = (nbid / gx) * 128, tn = (nbid % gx) * 128;
  const int wm = (w >> 1) * 64, wn = (w & 1) * 64;

  const short* Bsel = (tm < Msplit) ? Bt : Bt2;
  const float* bsel = (tm < Msplit) ? bias : bias2;

  const int r0 = w*32 + (l >> 2);
  const int r1 = r0 + 16;
  const int cb = (l & 3) * 16;

  const char* Ag0 = (const char*)(A + (size_t)(tm + r0) * K) + cb;
  const char* Ag1 = (const char*)(A + (size_t)(tm + r1) * K) + cb;
  const char* Bg0 = (const char*)(Bsel + (size_t)(tn + r0) * K) + cb;
  const char* Bg1 = (const char*)(Bsel + (size_t)(tn + r1) * K) + cb;
  char* Al0 = (char*)As + (w*2  )*1024;
  char* Al1 = (char*)As + (w*2+1)*1024;
  char* Bl0 = (char*)Bs + (w*2  )*1024;
  char* Bl1 = (char*)Bs + (w*2+1)*1024;

  f32x4 acc[4][4];
  #pragma unroll
  for (int m=0;m<4;m++){
    #pragma unroll
    for (int n=0;n<4;n++){ acc[m][n][0]=0.f; acc[m][n][1]=0.f; acc[m][n][2]=0.f; acc[m][n][3]=0.f; }
  }

  for (int k0 = 0; k0 < K; k0 += 32){
    const int kb = k0 * 2;
    gload16(Ag0 + kb, Al0);
    gload16(Ag1 + kb, Al1);
    gload16(Bg0 + kb, Bl0);
    gload16(Bg1 + kb, Bl1);
    __syncthreads();
    short8 af[4], bfr[4];
    #pragma unroll
    for (int m=0;m<4;m++) af[m]  = *(const short8*)(As + (wm + m*16 + lc)*32 + g*8);
    #pragma unroll
    for (int n=0;n<4;n++) bfr[n] = *(const short8*)(Bs + (wn + n*16 + lc)*32 + g*8);
    #pragma unroll
    for (int m=0;m<4;m++){
      #pragma unroll
      for (int n=0;n<4;n++)
        acc[m][n] = __builtin_amdgcn_mfma_f32_16x16x32_bf16(af[m], bfr[n], acc[m][n], 0, 0, 0);
    }
    __syncthreads();
  }

  #pragma unroll
  for (int n=0;n<4;n++){
    const int col = tn + wn + n*16 + lc;
    const float bv = bsel[col];
    #pragma unroll
    for (int m=0;m<4;m++){
      const int row = tm + wm + m*16 + g*4;
      #pragma unroll
      for (int r=0;r<4;r++)
        Cp[(size_t)(row + r)*N + col] = acc[m][n][r] + bv;
    }
  }
}

// ---------------- flash attention: lane-local P + single-buffered V -------
// r18 structure (sigma-permuted PV, zero bank conflicts) with V single-
// buffered -> LDS 48KB -> 3 blocks/CU, whole 576-block grid co-resident
// (no straggler round). Barrier schedule per iter:
//   issue loads -> QK^T(Kl[cur]) -> K-write(cur^1) -> softmax
//   -> barrier_A (prev V-writes visible) -> PV(Vl)
//   -> barrier_B (all PV reads done)    -> V-write(next)
// K-writes are covered by barrier_B of the previous iteration.
__global__ __launch_bounds__(512) void k_attn(const short* __restrict__ Q,
                                              const short* __restrict__ Kg,
                                              const short* __restrict__ Vt,
                                              short* __restrict__ o1,
                                              short* __restrict__ o2){
  __shared__ __align__(16) short Kl[2][8192];
  __shared__ __align__(16) short Vl[2][4096];
  const int t = threadIdx.x, w = t >> 6, l = t & 63;
  const int lc = l & 15, g = l >> 4;
  const int blk = blockIdx.x;
  const int ch = blk & 7, ii = blk >> 3;    // 576 = 8 * 72
  const int bh = ch * 4 + (ii / 18);        // 4 bh per XCD-chunk
  const int qt = ii % 18;
  const int b = bh >> 4, hh = bh & 15;
  const int q0 = qt * 128 + w * 16;
  const short* Qb = Q  + (size_t)bh * NT * HD;
  const short* Kb = Kg + (size_t)bh * NT * HD;
  const short* Vb = Vt + (size_t)bh * HD * NT;

  // Q fragment (B-operand): col q=lc, k-elems = head-dims g*8.. / +32
  short8 qf0 = *(const short8*)(Qb + (size_t)(q0 + lc) * HD + g*8);
  short8 qf1 = *(const short8*)(Qb + (size_t)(q0 + lc) * HD + g*8 + 32);

  // K staging role: row sr (0..127), chunks c0, c0+1 (32B per thread)
  const int sr = t >> 2, c0 = (t & 3) * 2;
  const short* Kgp = Kb + (size_t)sr * HD + c0 * 8;
  const int kw0 = swz(sr, c0), kw1 = swz(sr, c0 + 1);
  // V staging role: row vr (0..63), chunk vc0 (16B per thread per half-tile)
  const int vr = t >> 3, vc0 = t & 7;
  const short* Vgp = Vb + (size_t)vr * NT + vc0 * 8;   // + pi*128 + h*64
  const int vw0 = swz(vr, vc0);

  float mcur = -1e30f, lcur = 0.f;
  f32x4 oacc[4];
  #pragma unroll
  for (int j=0;j<4;j++){ oacc[j][0]=0.f; oacc[j][1]=0.f; oacc[j][2]=0.f; oacc[j][3]=0.f; }

  // prologue: stage pair 0 (K into buf 0; V into the single buffer)
  {
    short8 k0 = *(const short8*)(Kgp);
    short8 k1 = *(const short8*)(Kgp + 8);
    short8 v0 = *(const short8*)(Vgp);
    short8 v1 = *(const short8*)(Vgp + 64);
    *(short8*)&Kl[0][kw0] = k0;
    *(short8*)&Kl[0][kw1] = k1;
    *(short8*)&Vl[0][vw0] = v0;
    *(short8*)&Vl[1][vw0] = v1;
  }
  __syncthreads();

  for (int pi = 0; pi < 18; ++pi){
    const int cur = pi & 1;
    // issue next pair's global loads early (hide latency under compute)
    short8 kn0, kn1, vn0, vn1;
    if (pi < 17){
      const short* kp = Kgp + (size_t)(pi + 1) * 128 * HD;
      const short* vp = Vgp + (pi + 1) * 128;
      kn0 = *(const short8*)(kp);
      kn1 = *(const short8*)(kp + 8);
      vn0 = *(const short8*)(vp);
      vn1 = *(const short8*)(vp + 64);
    }
    // ---- S^T over 128 kv: s[j][r] = S[q=lc][kv = pi*128 + 16j + 4g + r] ----
    f32x4 s[8];
    __builtin_amdgcn_s_setprio(1);
    #pragma unroll
    for (int j=0;j<8;j++){
      const int row = j*16 + lc;
      short8 k0 = *(const short8*)(&Kl[cur][swz(row, g)]);
      short8 k1 = *(const short8*)(&Kl[cur][swz(row, g + 4)]);
      f32x4 a; a[0]=0.f; a[1]=0.f; a[2]=0.f; a[3]=0.f;
      a = __builtin_amdgcn_mfma_f32_16x16x32_bf16(k0, qf0, a, 0, 0, 0);
      a = __builtin_amdgcn_mfma_f32_16x16x32_bf16(k1, qf1, a, 0, 0, 0);
      s[j] = a;
    }
    __builtin_amdgcn_s_setprio(0);
    // ---- K-write next tile into the other K buffer (dbuf-safe) ----
    if (pi < 17){
      *(short8*)&Kl[cur ^ 1][kw0] = kn0;
      *(short8*)&Kl[cur ^ 1][kw1] = kn1;
    }
    // ---- joint lane-local softmax over 128 kv for q-row lc ----
    float tj[8];
    #pragma unroll
    for (int j=0;j<8;j++)
      tj[j] = fmaxf(fmaxf(s[j][0], s[j][1]), fmaxf(s[j][2], s[j][3]));
    float tmx = fmaxf(fmaxf(fmaxf(tj[0], tj[1]), fmaxf(tj[2], tj[3])),
                      fmaxf(fmaxf(tj[4], tj[5]), fmaxf(tj[6], tj[7])));
    tmx = fmaxf(tmx, __shfl_xor(tmx, 16, 64));
    tmx = fmaxf(tmx, __shfl_xor(tmx, 32, 64));
    float mn = mcur;
    if (__any(tmx > mcur + RESCALE_THR)){
      mn = fmaxf(mcur, tmx);
      const float fsc = fexp2(mcur - mn);
      mcur = mn;
      lcur *= fsc;
      #pragma unroll
      for (int j=0;j<4;j++){
        oacc[j][0] *= fsc; oacc[j][1] *= fsc; oacc[j][2] *= fsc; oacc[j][3] *= fsc;
      }
    }
    // p = exp2(s - mn), in place
    #pragma unroll
    for (int j=0;j<8;j++){
      s[j][0] = fexp2(s[j][0] - mn);
      s[j][1] = fexp2(s[j][1] - mn);
      s[j][2] = fexp2(s[j][2] - mn);
      s[j][3] = fexp2(s[j][3] - mn);
    }
    float rs = 0.f;
    #pragma unroll
    for (int j=0;j<8;j++)
      rs += (s[j][0] + s[j][1]) + (s[j][2] + s[j][3]);
    rs += __shfl_xor(rs, 16, 64);
    rs += __shfl_xor(rs, 32, 64);
    lcur += rs;
    // ---- barrier_A: previous iteration's V-writes visible ----
    __syncthreads();
    // ---- PV: sigma-permuted slots -> P fragment is fully lane-local ----
    #pragma unroll
    for (int h=0;h<2;h++){
      #pragma unroll
      for (int kk=0;kk<2;kk++){
        const int j0 = h*4 + kk*2;
        union { unsigned int u[4]; short8 s8; } pf;
        pf.u[0] = cvtpk2(s[j0  ][0], s[j0  ][1]);
        pf.u[1] = cvtpk2(s[j0  ][2], s[j0  ][3]);
        pf.u[2] = cvtpk2(s[j0+1][0], s[j0+1][1]);
        pf.u[3] = cvtpk2(s[j0+1][2], s[j0+1][3]);
        __builtin_amdgcn_s_setprio(1);
        #pragma unroll
        for (int jd=0;jd<4;jd++){
          short8 vb = *(const short8*)(&Vl[h][swz(lc + 16*jd, 4*kk + g)]);
          oacc[jd] = __builtin_amdgcn_mfma_f32_16x16x32_bf16(vb, pf.s8, oacc[jd], 0, 0, 0);
        }
        __builtin_amdgcn_s_setprio(0);
      }
    }
    // ---- barrier_B: all PV reads done; then write next V ----
    __syncthreads();
    if (pi < 17){
      *(short8*)&Vl[0][vw0] = vn0;
      *(short8*)&Vl[1][vw0] = vn1;
    }
  }

  // ---- epilogue: normalize (lane-local) and write ----
  const float inv = 1.0f / lcur;
  const int qi = q0 + lc;
  short* obase = (qi < N1) ? (o1 + ((size_t)b * N1 + qi) * D_)
                           : (o2 + ((size_t)b * N2 + (qi - N1)) * D_);
  #pragma unroll
  for (int jd=0;jd<4;jd++){
    bf4 ov;
    #pragma unroll
    for (int r=0;r<4;r++) ov[r] = f2bf(oacc[jd][r] * inv);
    *(bf4*)(obase + hh*64 + 16*jd + 4*g) = ov;
  }
}

extern "C" void kernel_launch(void* const* d_in, const int* in_sizes, int n_in,
                              void* d_out, int out_size, void* d_ws, size_t ws_size,
                              hipStream_t stream){
  const float* x    = (const float*)d_in[0];
  const float* c    = (const float*)d_in[1];
  const float* fc   = (const float*)d_in[2];
  const float* fs   = (const float*)d_in[3];
  const float* Wq1  = (const float*)d_in[4];
  const float* bq1  = (const float*)d_in[5];
  const float* Wq2  = (const float*)d_in[6];
  const float* bq2  = (const float*)d_in[7];
  const float* qn1w = (const float*)d_in[8];
  const float* qn1b = (const float*)d_in[9];
  const float* kn1w = (const float*)d_in[10];
  const float* kn1b = (const float*)d_in[11];
  const float* qn2w = (const float*)d_in[12];
  const float* qn2b = (const float*)d_in[13];
  const float* kn2w = (const float*)d_in[14];
  const float* kn2b = (const float*)d_in[15];
  const float* Wp1  = (const float*)d_in[16];
  const float* bp1  = (const float*)d_in[17];
  const float* Wp2  = (const float*)d_in[18];
  const float* bp2  = (const float*)d_in[19];
  float* out = (float*)d_out;

  char* ws = (char*)d_ws;
  short* xb   = (short*)(ws);                       // 8,388,608 + cb 1,048,576 contiguous
  short* Wt1  = (short*)(ws + 9437184);             // 6,291,456
  short* Wt2  = (short*)(ws + 15728640);            // 6,291,456
  short* Wtp1 = (short*)(ws + 22020096);            // 2,097,152
  short* Wtp2 = (short*)(ws + 24117248);            // 2,097,152
  short* o1   = (short*)(ws + 26214400);            // 8,388,608 (+o2 1,048,576 contiguous)
  short* Vtb  = (short*)(ws + 26214400 + 9437184);  // 9,437,184
  short* Qb   = (short*)(ws + 54525952);            // 9,437,184
  short* Kb   = (short*)(ws + 63963136);            // 9,437,184

  k_cvt_all<<<2304, 256, 0, stream>>>(x, c, xb);
  k_transpose_w4<<<2048, 256, 0, stream>>>(Wq1, Wq2, Wp1, Wp2, Wt1, Wt2, Wtp1, Wtp2);

  // fused QKV GEMM + bias + LN + RoPE + split + V-transpose (pi-permuted)
  k_gemm_qkv<<<dim3(24,36), 256, 0, stream>>>(xb, Wt1, Wt2, bq1, bq2,
      qn1w, qn1b, kn1w, kn1b, qn2w, qn2b, kn2w, kn2b, fc, fs, Qb, Kb, Vtb);

  k_attn<<<576, 512, 0, stream>>>(Qb, Kb, Vtb, o1, o1 + 4194304);

  // fused projection GEMM: A = [o1; o2] (4608 x 1024), rows >= 4096 use Wtp2/bp2
  k_gemm_proj<<<dim3(8,36), 256, 0, stream>>>(o1, Wtp1, Wtp2, bp1, bp2, out, 1024, 1024, 4096);
}